// Round 7
// baseline (659.974 us; speedup 1.0000x reference)
//
#include <hip/hip_runtime.h>

typedef unsigned long long u64;
typedef unsigned short ushort_t;

#define NA 50000
#define NE 400000
#define DF 128
#define HID 64
#define NMOL 256
#define NOUT 32
#define NSTEP 3
#define SLOTS 48
#define TPITCH 132

typedef __attribute__((ext_vector_type(8))) short short8;
typedef __attribute__((ext_vector_type(8))) unsigned short ushort8;
typedef __attribute__((ext_vector_type(4))) float f32x4;

static __device__ __forceinline__ ushort_t f2bf(float f) {
  union { float f; unsigned u; } v; v.f = f;
  unsigned r = v.u + 0x7fffu + ((v.u >> 16) & 1u);
  return (ushort_t)(r >> 16);
}
static __device__ __forceinline__ float bf2f(unsigned b) {
  union { unsigned u; float f; } v; v.u = b << 16;
  return v.f;
}

// -------- fused setup: pack weights (B-frag order) + degree histograms -----
__global__ void setup_a(const float* __restrict__ Win, const float* __restrict__ Wh,
                        const float* __restrict__ Wout,
                        ushort_t* __restrict__ WpB, ushort_t* __restrict__ WhB,
                        ushort_t* __restrict__ WoB,
                        const int* __restrict__ dst, const int* __restrict__ mol_ids,
                        int* __restrict__ counts, int* __restrict__ mcnt) {
  int g = blockIdx.x * 256 + threadIdx.x;
  if (g < 3 * 16384) {
    int tt = g / 16384, r = g % 16384;
    int j = r & 7, lane = (r >> 3) & 63, f = r >> 9;
    int kc = f & 3, nt = f >> 2;
    int k = kc * 32 + (lane >> 4) * 8 + j;
    int n = nt * 16 + (lane & 15);
    float v = (n < 64) ? Win[tt * 16384 + k * 64 + n]
                       : Win[tt * 16384 + (128 + k) * 64 + (n - 64)];
    WpB[g] = f2bf(v);
  }
  int g2 = g - 3 * 16384;
  if (g2 >= 0 && g2 < 3 * 4096) {
    int tt = g2 / 4096, r = g2 % 4096;
    int j = r & 7, lane = (r >> 3) & 63, f = r >> 9;
    int kc = f & 1, nt = f >> 1;
    int k = kc * 32 + (lane >> 4) * 8 + j;
    int n = nt * 16 + (lane & 15);
    WhB[g2] = f2bf(Wh[tt * 4096 + k * 64 + n]);
  }
  int g3 = g2 - 3 * 4096;
  if (g3 >= 0 && g3 < 3 * 8192) {
    int tt = g3 / 8192, r = g3 % 8192;
    int j = r & 7, lane = (r >> 3) & 63, f = r >> 9;
    int kc = f & 1, nt = f >> 1;
    int k = kc * 32 + (lane >> 4) * 8 + j;
    int n = nt * 16 + (lane & 15);
    WoB[g3] = f2bf(Wout[tt * 8192 + k * 128 + n]);
  }
  if (g < NE) atomicAdd(&counts[dst[g]], 1);
  if (g < NA) atomicAdd(&mcnt[mol_ids[g]], 1);
}

__global__ void scan_phase1(const int* __restrict__ counts, int* __restrict__ tmp,
                            int* __restrict__ blk) {
  __shared__ int sh[1024];
  int t = threadIdx.x;
  int i = blockIdx.x * 1024 + t;
  sh[t] = (i < NA) ? counts[i] : 0;
  __syncthreads();
  for (int off = 1; off < 1024; off <<= 1) {
    int x = (t >= off) ? sh[t - off] : 0;
    __syncthreads();
    sh[t] += x;
    __syncthreads();
  }
  if (i < NA) tmp[i] = sh[t];
  if (t == 1023) blk[blockIdx.x] = sh[1023];
}

// block offsets (serial over 49) + molecule scan (Hillis over 256), one block
__global__ void scan_p2m(int* __restrict__ blk, int nblk,
                         const int* __restrict__ mcnt, int* __restrict__ mrow) {
  __shared__ int sh[64];
  __shared__ int ms[NMOL];
  int t = threadIdx.x;
  if (t < 64) sh[t] = (t < nblk) ? blk[t] : 0;
  ms[t] = mcnt[t];
  __syncthreads();
  if (t == 0) {
    int run = 0;
    for (int k = 0; k < nblk; k++) { int c = sh[k]; sh[k] = run; run += c; }
  }
  for (int off = 1; off < NMOL; off <<= 1) {
    int x = (t >= off) ? ms[t - off] : 0;
    __syncthreads();
    ms[t] += x;
    __syncthreads();
  }
  if (t < nblk) blk[t] = sh[t];
  mrow[t + 1] = ms[t];
  if (t == 0) mrow[0] = 0;
}

__global__ void scan_phase3(const int* __restrict__ tmp, const int* __restrict__ blk,
                            int* __restrict__ row_ptr) {
  int i = blockIdx.x * 1024 + threadIdx.x;
  if (i < NA) row_ptr[i + 1] = tmp[i] + blk[blockIdx.x];
  if (i == 0 && blockIdx.x == 0) row_ptr[0] = 0;
}

__global__ void fill_ab(const int* __restrict__ src, const int* __restrict__ dst,
                        const int* __restrict__ row_ptr, int* __restrict__ cursor,
                        int* __restrict__ dst_s, int* __restrict__ src_s,
                        const int* __restrict__ mol_ids, const int* __restrict__ mrow,
                        int* __restrict__ mcur, int* __restrict__ mol_sorted) {
  int e = blockIdx.x * 256 + threadIdx.x;
  if (e < NE) {
    int d = dst[e];
    int pos = row_ptr[d] + atomicAdd(&cursor[d], 1);
    dst_s[pos] = d;
    src_s[pos] = src[e];
  }
  if (e < NA) {
    int m = mol_ids[e];
    int pos = mrow[m] + atomicAdd(&mcur[m], 1);
    mol_sorted[pos] = e;
  }
}

// -------- node projection: PQb = bf16(s @ W') + zero s_next rows -----------
// s_in may alias s_zero (NOT restrict): read fragments, barrier-drain, zero.
__global__ __launch_bounds__(256) void node_proj(const float* s_in,
                                                 const ushort_t* __restrict__ WpB,
                                                 ushort_t* __restrict__ PQb,
                                                 float* s_zero) {
  const int t = threadIdx.x;
  const int lane = t & 63, wv = t >> 6, quad = lane >> 4, l15 = lane & 15;
  const int n0 = blockIdx.x * 64 + wv * 16;
  int n = n0 + l15; if (n >= NA) n = NA - 1;
  union { short8 v; ushort_t u[8]; } a[4];
#pragma unroll
  for (int c = 0; c < 4; c++) {
    const float* p = s_in + (u64)n * 128 + c * 32 + quad * 8;
    float4 f0 = *(const float4*)(p);
    float4 f1 = *(const float4*)(p + 4);
    a[c].u[0] = f2bf(f0.x); a[c].u[1] = f2bf(f0.y);
    a[c].u[2] = f2bf(f0.z); a[c].u[3] = f2bf(f0.w);
    a[c].u[4] = f2bf(f1.x); a[c].u[5] = f2bf(f1.y);
    a[c].u[6] = f2bf(f1.z); a[c].u[7] = f2bf(f1.w);
  }
  __syncthreads();  // all fragment loads returned before zeroing (may alias)
  {
    float4 z4 = {0.f, 0.f, 0.f, 0.f};
    const int nb = blockIdx.x * 64;
    for (int idx = t; idx < 64 * 32; idx += 256) {
      int row = nb + (idx >> 5);
      if (row < NA) ((float4*)(s_zero + (u64)row * 128))[idx & 31] = z4;
    }
  }
#pragma unroll
  for (int nt = 0; nt < 8; nt++) {
    f32x4 acc = {0.f, 0.f, 0.f, 0.f};
#pragma unroll
    for (int c = 0; c < 4; c++) {
      short8 b = *(const short8*)&WpB[((nt * 4 + c) * 64 + lane) * 8];
      acc = __builtin_amdgcn_mfma_f32_16x16x32_bf16(a[c].v, b, acc, 0, 0, 0);
    }
#pragma unroll
    for (int r = 0; r < 4; r++) {
      int nn = n0 + quad * 4 + r;
      if (nn < NA) PQb[(u64)nn * 128 + nt * 16 + l15] = f2bf(acc[r]);
    }
  }
}

// ------ fused edge MLP (MFMA) + block-local run aggregation -> s_next ------
// 128 sorted edges / block. Run table in LDS (fp32); interior runs: plain
// store; block-boundary runs: atomicAdd onto zeroed s_next.
__global__ __launch_bounds__(256) void edge_msg(
    const ushort_t* __restrict__ PQb,
    const ushort_t* __restrict__ WhB, const ushort_t* __restrict__ WoB,
    const float* __restrict__ b_in, const float* __restrict__ b_h,
    const float* __restrict__ b_out,
    const int* __restrict__ dst_s, const int* __restrict__ src_s,
    float* __restrict__ s_next) {
  __shared__ int eds[128], ess[128], rid[128];
  __shared__ int rdst[SLOTS];
  __shared__ float tbl[SLOTS * TPITCH];
  __shared__ int nruns_sh;
  __shared__ ushort_t h2s[8][16 * 72];
  const int t = threadIdx.x;
  const int lane = t & 63, wv = t >> 6, quad = lane >> 4, l15 = lane & 15;
  const long long e0 = (long long)blockIdx.x * 128;

  if (t < 128) {
    long long e = e0 + t; if (e >= NE) e = NE - 1;
    eds[t] = dst_s[e]; ess[t] = src_s[e];
  }
  for (int idx = t; idx < SLOTS * TPITCH; idx += 256) tbl[idx] = 0.f;
  float bh[4], bo[8];
#pragma unroll
  for (int nt = 0; nt < 4; nt++) bh[nt] = b_h[nt * 16 + l15];
#pragma unroll
  for (int nt = 0; nt < 8; nt++) bo[nt] = b_out[nt * 16 + l15];
  __syncthreads();
  // block-local run ids: rid[e] = #distinct dsts before e (inclusive scan - 1)
  if (t < 128) rid[t] = (t == 0 || eds[t] != eds[t - 1]) ? 1 : 0;
  __syncthreads();
  for (int off = 1; off < 128; off <<= 1) {
    int x = (t < 128 && t >= off) ? rid[t - off] : 0;
    __syncthreads();
    if (t < 128) rid[t] += x;
    __syncthreads();
  }
  if (t < 128) {
    rid[t] -= 1;
    if ((t == 0 || eds[t] != eds[t - 1]) && rid[t] < SLOTS) rdst[rid[t]] = eds[t];
  }
  __syncthreads();
  if (t == 0) nruns_sh = rid[127] + 1;

#pragma unroll
  for (int i = 0; i < 2; i++) {
    const int ebl = wv * 32 + i * 16;
    const int da = eds[ebl + l15], sa = ess[ebl + l15];

    // A-frag of h1 = relu(P[dst] + Q[src] + b_in); 16B bf16 gathers
    union { short8 v; ushort_t u[8]; } a1[2];
#pragma unroll
    for (int c = 0; c < 2; c++) {
      const int col = c * 32 + quad * 8;
      union { ushort8 v; ushort_t u[8]; } pv, qv;
      pv.v = *(const ushort8*)&PQb[(u64)da * 128 + col];
      qv.v = *(const ushort8*)&PQb[(u64)sa * 128 + 64 + col];
      float4 bi0 = *(const float4*)(b_in + col);
      float4 bi1 = *(const float4*)(b_in + col + 4);
      a1[c].u[0] = f2bf(fmaxf(bf2f(pv.u[0]) + bf2f(qv.u[0]) + bi0.x, 0.f));
      a1[c].u[1] = f2bf(fmaxf(bf2f(pv.u[1]) + bf2f(qv.u[1]) + bi0.y, 0.f));
      a1[c].u[2] = f2bf(fmaxf(bf2f(pv.u[2]) + bf2f(qv.u[2]) + bi0.z, 0.f));
      a1[c].u[3] = f2bf(fmaxf(bf2f(pv.u[3]) + bf2f(qv.u[3]) + bi0.w, 0.f));
      a1[c].u[4] = f2bf(fmaxf(bf2f(pv.u[4]) + bf2f(qv.u[4]) + bi1.x, 0.f));
      a1[c].u[5] = f2bf(fmaxf(bf2f(pv.u[5]) + bf2f(qv.u[5]) + bi1.y, 0.f));
      a1[c].u[6] = f2bf(fmaxf(bf2f(pv.u[6]) + bf2f(qv.u[6]) + bi1.z, 0.f));
      a1[c].u[7] = f2bf(fmaxf(bf2f(pv.u[7]) + bf2f(qv.u[7]) + bi1.w, 0.f));
    }

    // h2 = relu(h1 @ Wh + b_h)
    f32x4 acc1[4];
#pragma unroll
    for (int nt = 0; nt < 4; nt++) {
      f32x4 acc = {0.f, 0.f, 0.f, 0.f};
#pragma unroll
      for (int c = 0; c < 2; c++) {
        short8 b = *(const short8*)&WhB[((nt * 2 + c) * 64 + lane) * 8];
        acc = __builtin_amdgcn_mfma_f32_16x16x32_bf16(a1[c].v, b, acc, 0, 0, 0);
      }
      acc1[nt] = acc;
    }
    // D-layout -> row-major LDS (wave-private; same-wave RAW via lgkmcnt)
    ushort_t* hb = h2s[wv * 2 + i];
#pragma unroll
    for (int nt = 0; nt < 4; nt++)
#pragma unroll
      for (int r = 0; r < 4; r++)
        hb[(quad * 4 + r) * 72 + nt * 16 + l15] =
            f2bf(fmaxf(acc1[nt][r] + bh[nt], 0.f));

    union { short8 v; ushort_t u[8]; } a2[2];
#pragma unroll
    for (int c = 0; c < 2; c++)
      a2[c].v = *(const short8*)&hb[l15 * 72 + c * 32 + quad * 8];

    // m = relu(h2 @ Wout + b_out)
    f32x4 acc2[8];
#pragma unroll
    for (int nt = 0; nt < 8; nt++) {
      f32x4 acc = {0.f, 0.f, 0.f, 0.f};
#pragma unroll
      for (int c = 0; c < 2; c++) {
        short8 b = *(const short8*)&WoB[((nt * 2 + c) * 64 + lane) * 8];
        acc = __builtin_amdgcn_mfma_f32_16x16x32_bf16(a2[c].v, b, acc, 0, 0, 0);
      }
      acc2[nt] = acc;
    }

    // register-segmented accumulate into LDS run table (fallback: global)
    {
      const int base = ebl + quad * 4;
      int prev_r = rid[base];
      int prev_d = eds[base];
      float run[8];
#pragma unroll
      for (int nt = 0; nt < 8; nt++) run[nt] = 0.f;
#pragma unroll
      for (int r = 0; r < 4; r++) {
        int er = base + r;
        int rr = rid[er];
        if (rr != prev_r) {
          if (prev_r < SLOTS) {
#pragma unroll
            for (int nt = 0; nt < 8; nt++)
              atomicAdd(&tbl[prev_r * TPITCH + nt * 16 + l15], run[nt]);
          } else {
#pragma unroll
            for (int nt = 0; nt < 8; nt++)
              atomicAdd(&s_next[(u64)prev_d * 128 + nt * 16 + l15], run[nt]);
          }
#pragma unroll
          for (int nt = 0; nt < 8; nt++) run[nt] = 0.f;
          prev_r = rr; prev_d = eds[er];
        }
        if (e0 + er < NE) {
#pragma unroll
          for (int nt = 0; nt < 8; nt++)
            run[nt] += fmaxf(acc2[nt][r] + bo[nt], 0.f);
        }
      }
      if (prev_r < SLOTS) {
#pragma unroll
        for (int nt = 0; nt < 8; nt++)
          atomicAdd(&tbl[prev_r * TPITCH + nt * 16 + l15], run[nt]);
      } else {
#pragma unroll
        for (int nt = 0; nt < 8; nt++)
          atomicAdd(&s_next[(u64)prev_d * 128 + nt * 16 + l15], run[nt]);
      }
    }
  }
  __syncthreads();

  // block flush: interior runs plain-store, boundary runs atomicAdd
  {
    int nr = nruns_sh;
    int d_prev = (e0 > 0) ? dst_s[e0 - 1] : -1;
    int d_next = (e0 + 128 < NE) ? dst_s[e0 + 128] : -1;
    int lim = (nr < SLOTS) ? nr : SLOTS;
    for (int idx = t; idx < lim * 128; idx += 256) {
      int r = idx >> 7, c = idx & 127;
      float v = tbl[r * TPITCH + c];
      int d = rdst[r];
      bool bnd = (r == 0 && d == d_prev) || (r == nr - 1 && d == d_next);
      if (bnd) atomicAdd(&s_next[(u64)d * 128 + c], v);
      else s_next[(u64)d * 128 + c] = v;
    }
  }
}

// ------- molecule aggregation: chunked segmented sum over mol_sorted -------
__global__ __launch_bounds__(128) void agg_mol(const float* __restrict__ s_fin,
                                               const int* __restrict__ mol_sorted,
                                               const int* __restrict__ mol_ids,
                                               float* __restrict__ mol_repr) {
  __shared__ int rows[128], mids[128];
  const int c = threadIdx.x;
  const int base = blockIdx.x * 128;
  int n = NA - base; if (n > 128) n = 128;
  if (c < n) {
    int r = mol_sorted[base + c];
    rows[c] = r;
    mids[c] = mol_ids[r];
  }
  __syncthreads();
  float run = 0.f;
  int prev = mids[0];
#pragma unroll 4
  for (int i = 0; i < n; i++) {
    int m = mids[i];
    if (m != prev) {
      atomicAdd(&mol_repr[(u64)prev * 128 + c], run);
      run = 0.f; prev = m;
    }
    run += s_fin[(u64)rows[i] * 128 + c];
  }
  atomicAdd(&mol_repr[(u64)prev * 128 + c], run);
}

// ---------------- final tiny MLP per molecule ----------------
__global__ void final_mlp(const float* __restrict__ mol_repr,
                          const float* __restrict__ fc1_w, const float* __restrict__ fc1_b,
                          const float* __restrict__ fc2_w, const float* __restrict__ fc2_b,
                          const float* __restrict__ out_w, const float* __restrict__ out_b,
                          float* __restrict__ out) {
  int m = blockIdx.x, j = threadIdx.x;
  __shared__ float h1sh[64], h2sh[64];
  const float* mr = mol_repr + (u64)m * DF;
  float acc = fc1_b[j];
  for (int d = 0; d < DF; d++) acc = fmaf(mr[d], fc1_w[d * 64 + j], acc);
  h1sh[j] = fmaxf(acc, 0.f);
  __syncthreads();
  acc = fc2_b[j];
  for (int k = 0; k < 64; k++) acc = fmaf(h1sh[k], fc2_w[k * 64 + j], acc);
  h2sh[j] = fmaxf(acc, 0.f);
  __syncthreads();
  if (j < NOUT) {
    acc = out_b[j];
    for (int k = 0; k < 64; k++) acc = fmaf(h2sh[k], out_w[k * NOUT + j], acc);
    out[(u64)m * NOUT + j] = acc;
  }
}

extern "C" void kernel_launch(void* const* d_in, const int* in_sizes, int n_in,
                              void* d_out, int out_size, void* d_ws, size_t ws_size,
                              hipStream_t stream) {
  const float* states = (const float*)d_in[0];
  const float* Win    = (const float*)d_in[1];
  const float* b_in   = (const float*)d_in[2];
  const float* Wh     = (const float*)d_in[3];
  const float* b_h    = (const float*)d_in[4];
  const float* Wout   = (const float*)d_in[5];
  const float* b_out  = (const float*)d_in[6];
  const float* fc1_w  = (const float*)d_in[7];
  const float* fc1_b  = (const float*)d_in[8];
  const float* fc2_w  = (const float*)d_in[9];
  const float* fc2_b  = (const float*)d_in[10];
  const float* out_w  = (const float*)d_in[11];
  const float* out_b  = (const float*)d_in[12];
  const int* src      = (const int*)d_in[13];
  const int* dst      = (const int*)d_in[14];
  const int* mol_ids  = (const int*)d_in[15];

  char* ws = (char*)d_ws;
  u64 o = 0;
  auto alloc = [&](u64 bytes) {
    void* p = ws + o;
    o += (bytes + 255) & ~255ull;
    return p;
  };
  ushort_t* PQb  = (ushort_t*)alloc((u64)NA * DF * 2);
  float* sA      = (float*)alloc((u64)NA * DF * 4);
  ushort_t* WpB  = (ushort_t*)alloc(3 * 16384 * 2);
  ushort_t* WhB  = (ushort_t*)alloc(3 * 4096 * 2);
  ushort_t* WoB  = (ushort_t*)alloc(3 * 8192 * 2);
  // zero-init block (single memset)
  char* zbase    = ws + o;
  float* molr    = (float*)alloc((u64)NMOL * DF * 4);
  int* counts    = (int*)alloc((u64)NA * 4);
  int* cursor    = (int*)alloc((u64)NA * 4);
  int* mcnt      = (int*)alloc(NMOL * 4);
  int* mcur      = (int*)alloc(NMOL * 4);
  u64 zbytes     = (u64)((ws + o) - zbase);
  int* row_ptr   = (int*)alloc((u64)(NA + 1) * 4);
  int* mrow      = (int*)alloc((NMOL + 1) * 4);
  int* dst_s     = (int*)alloc((u64)NE * 4);
  int* src_s     = (int*)alloc((u64)NE * 4);
  int* mol_sorted = (int*)alloc((u64)NA * 4);
  int* scan_tmp  = (int*)alloc((u64)NA * 4);
  int* blk_sums  = (int*)alloc(64 * 4);
  (void)ws_size; (void)in_sizes; (void)n_in; (void)out_size;

  const int NSCAN = (NA + 1023) / 1024;  // 49

  hipMemsetAsync(zbase, 0, zbytes, stream);

  setup_a<<<(NE + 255) / 256, 256, 0, stream>>>(Win, Wh, Wout, WpB, WhB, WoB,
                                                dst, mol_ids, counts, mcnt);
  scan_phase1<<<NSCAN, 1024, 0, stream>>>(counts, scan_tmp, blk_sums);
  scan_p2m<<<1, 256, 0, stream>>>(blk_sums, NSCAN, mcnt, mrow);
  scan_phase3<<<NSCAN, 1024, 0, stream>>>(scan_tmp, blk_sums, row_ptr);
  fill_ab<<<(NE + 255) / 256, 256, 0, stream>>>(src, dst, row_ptr, cursor, dst_s, src_s,
                                                mol_ids, mrow, mcur, mol_sorted);

  const float* scur = states;
  for (int t = 0; t < NSTEP; t++) {
    node_proj<<<(NA + 63) / 64, 256, 0, stream>>>(scur, WpB + t * 16384, PQb, sA);
    edge_msg<<<(NE + 127) / 128, 256, 0, stream>>>(
        PQb, WhB + t * 4096, WoB + t * 8192,
        b_in + t * 64, b_h + t * 64, b_out + t * 128, dst_s, src_s, sA);
    scur = sA;
  }
  agg_mol<<<(NA + 127) / 128, 128, 0, stream>>>(sA, mol_sorted, mol_ids, molr);
  final_mlp<<<NMOL, 64, 0, stream>>>(molr, fc1_w, fc1_b, fc2_w, fc2_b, out_w, out_b,
                                     (float*)d_out);
}

// Round 8
// 468.280 us; speedup vs baseline: 1.4094x; 1.4094x over previous
//
#include <hip/hip_runtime.h>

typedef unsigned long long u64;
typedef unsigned short ushort_t;

#define NA 50000
#define NE 400000
#define DF 128
#define HID 64
#define NMOL 256
#define NOUT 32
#define NSTEP 3

typedef __attribute__((ext_vector_type(8))) short short8;
typedef __attribute__((ext_vector_type(8))) unsigned short ushort8;
typedef __attribute__((ext_vector_type(4))) float f32x4;

static __device__ __forceinline__ ushort_t f2bf(float f) {
  union { float f; unsigned u; } v; v.f = f;
  unsigned r = v.u + 0x7fffu + ((v.u >> 16) & 1u);
  return (ushort_t)(r >> 16);
}
static __device__ __forceinline__ float bf2f(unsigned b) {
  union { unsigned u; float f; } v; v.u = b << 16;
  return v.f;
}

// -------- fused setup: pack weights (B-frag order) + degree histograms -----
__global__ void setup_a(const float* __restrict__ Win, const float* __restrict__ Wh,
                        const float* __restrict__ Wout,
                        ushort_t* __restrict__ WpB, ushort_t* __restrict__ WhB,
                        ushort_t* __restrict__ WoB,
                        const int* __restrict__ dst, const int* __restrict__ mol_ids,
                        int* __restrict__ counts, int* __restrict__ mcnt) {
  int g = blockIdx.x * 256 + threadIdx.x;
  if (g < 3 * 16384) {
    int tt = g / 16384, r = g % 16384;
    int j = r & 7, lane = (r >> 3) & 63, f = r >> 9;
    int kc = f & 3, nt = f >> 2;
    int k = kc * 32 + (lane >> 4) * 8 + j;
    int n = nt * 16 + (lane & 15);
    float v = (n < 64) ? Win[tt * 16384 + k * 64 + n]
                       : Win[tt * 16384 + (128 + k) * 64 + (n - 64)];
    WpB[g] = f2bf(v);
  }
  int g2 = g - 3 * 16384;
  if (g2 >= 0 && g2 < 3 * 4096) {
    int tt = g2 / 4096, r = g2 % 4096;
    int j = r & 7, lane = (r >> 3) & 63, f = r >> 9;
    int kc = f & 1, nt = f >> 1;
    int k = kc * 32 + (lane >> 4) * 8 + j;
    int n = nt * 16 + (lane & 15);
    WhB[g2] = f2bf(Wh[tt * 4096 + k * 64 + n]);
  }
  int g3 = g2 - 3 * 4096;
  if (g3 >= 0 && g3 < 3 * 8192) {
    int tt = g3 / 8192, r = g3 % 8192;
    int j = r & 7, lane = (r >> 3) & 63, f = r >> 9;
    int kc = f & 1, nt = f >> 1;
    int k = kc * 32 + (lane >> 4) * 8 + j;
    int n = nt * 16 + (lane & 15);
    WoB[g3] = f2bf(Wout[tt * 8192 + k * 128 + n]);
  }
  if (g < NE) atomicAdd(&counts[dst[g]], 1);
  if (g < NA) atomicAdd(&mcnt[mol_ids[g]], 1);
}

__global__ void scan_phase1(const int* __restrict__ counts, int* __restrict__ tmp,
                            int* __restrict__ blk) {
  __shared__ int sh[1024];
  int t = threadIdx.x;
  int i = blockIdx.x * 1024 + t;
  sh[t] = (i < NA) ? counts[i] : 0;
  __syncthreads();
  for (int off = 1; off < 1024; off <<= 1) {
    int x = (t >= off) ? sh[t - off] : 0;
    __syncthreads();
    sh[t] += x;
    __syncthreads();
  }
  if (i < NA) tmp[i] = sh[t];
  if (t == 1023) blk[blockIdx.x] = sh[1023];
}

__global__ void scan_p2m(int* __restrict__ blk, int nblk,
                         const int* __restrict__ mcnt, int* __restrict__ mrow) {
  __shared__ int sh[64];
  __shared__ int ms[NMOL];
  int t = threadIdx.x;
  if (t < 64) sh[t] = (t < nblk) ? blk[t] : 0;
  ms[t] = mcnt[t];
  __syncthreads();
  if (t == 0) {
    int run = 0;
    for (int k = 0; k < nblk; k++) { int c = sh[k]; sh[k] = run; run += c; }
  }
  for (int off = 1; off < NMOL; off <<= 1) {
    int x = (t >= off) ? ms[t - off] : 0;
    __syncthreads();
    ms[t] += x;
    __syncthreads();
  }
  if (t < nblk) blk[t] = sh[t];
  mrow[t + 1] = ms[t];
  if (t == 0) mrow[0] = 0;
}

__global__ void scan_phase3(const int* __restrict__ tmp, const int* __restrict__ blk,
                            int* __restrict__ row_ptr) {
  int i = blockIdx.x * 1024 + threadIdx.x;
  if (i < NA) row_ptr[i + 1] = tmp[i] + blk[blockIdx.x];
  if (i == 0 && blockIdx.x == 0) row_ptr[0] = 0;
}

__global__ void fill_ab(const int* __restrict__ src, const int* __restrict__ dst,
                        const int* __restrict__ row_ptr, int* __restrict__ cursor,
                        int* __restrict__ dst_s, int* __restrict__ src_s,
                        const int* __restrict__ mol_ids, const int* __restrict__ mrow,
                        int* __restrict__ mcur, int* __restrict__ mol_sorted) {
  int e = blockIdx.x * 256 + threadIdx.x;
  if (e < NE) {
    int d = dst[e];
    int pos = row_ptr[d] + atomicAdd(&cursor[d], 1);
    dst_s[pos] = d;
    src_s[pos] = src[e];
  }
  if (e < NA) {
    int m = mol_ids[e];
    int pos = mrow[m] + atomicAdd(&mcur[m], 1);
    mol_sorted[pos] = e;
  }
}

// ---------------- node projection: PQb = bf16(s @ W')  (MFMA, LDS-free) ----
// Used once, on the initial fp32 states.
__global__ __launch_bounds__(256) void node_proj(const float* __restrict__ s_in,
                                                 const ushort_t* __restrict__ WpB,
                                                 ushort_t* __restrict__ PQb) {
  const int t = threadIdx.x;
  const int lane = t & 63, wv = t >> 6, quad = lane >> 4, l15 = lane & 15;
  const int n0 = blockIdx.x * 64 + wv * 16;
  int n = n0 + l15; if (n >= NA) n = NA - 1;
  union { short8 v; ushort_t u[8]; } a[4];
#pragma unroll
  for (int c = 0; c < 4; c++) {
    const float* p = s_in + (u64)n * 128 + c * 32 + quad * 8;
    float4 f0 = *(const float4*)(p);
    float4 f1 = *(const float4*)(p + 4);
    a[c].u[0] = f2bf(f0.x); a[c].u[1] = f2bf(f0.y);
    a[c].u[2] = f2bf(f0.z); a[c].u[3] = f2bf(f0.w);
    a[c].u[4] = f2bf(f1.x); a[c].u[5] = f2bf(f1.y);
    a[c].u[6] = f2bf(f1.z); a[c].u[7] = f2bf(f1.w);
  }
#pragma unroll
  for (int nt = 0; nt < 8; nt++) {
    f32x4 acc = {0.f, 0.f, 0.f, 0.f};
#pragma unroll
    for (int c = 0; c < 4; c++) {
      short8 b = *(const short8*)&WpB[((nt * 4 + c) * 64 + lane) * 8];
      acc = __builtin_amdgcn_mfma_f32_16x16x32_bf16(a[c].v, b, acc, 0, 0, 0);
    }
#pragma unroll
    for (int r = 0; r < 4; r++) {
      int nn = n0 + quad * 4 + r;
      if (nn < NA) PQb[(u64)nn * 128 + nt * 16 + l15] = f2bf(acc[r]);
    }
  }
}

// ------------- fused edge MLP (MFMA) -> streamed packed-bf16 messages ------
// 128 edges / workgroup (4 waves x 2 tiles of 16 edges). No atomics.
// (proven round-6 version, unchanged)
__global__ __launch_bounds__(256) void edge_msg(
    const ushort_t* __restrict__ PQb,
    const ushort_t* __restrict__ WhB, const ushort_t* __restrict__ WoB,
    const float* __restrict__ b_in, const float* __restrict__ b_h,
    const float* __restrict__ b_out,
    const int* __restrict__ dst_s, const int* __restrict__ src_s,
    unsigned* __restrict__ m_buf) {
  __shared__ int eds[128], ess[128];
  __shared__ ushort_t h2s[8][16 * 72];  // per-(wave,i) 16 x 64 bf16, pitch 72
  const int t = threadIdx.x;
  const int lane = t & 63, wv = t >> 6, quad = lane >> 4, l15 = lane & 15;
  const long long e0 = (long long)blockIdx.x * 128;

  if (t < 128) {
    long long e = e0 + t; if (e >= NE) e = NE - 1;
    eds[t] = dst_s[e]; ess[t] = src_s[e];
  }
  float bh[4], bo[8];
#pragma unroll
  for (int nt = 0; nt < 4; nt++) bh[nt] = b_h[nt * 16 + l15];
#pragma unroll
  for (int nt = 0; nt < 8; nt++) bo[nt] = b_out[nt * 16 + l15];
  __syncthreads();

#pragma unroll
  for (int i = 0; i < 2; i++) {
    const int ebl = wv * 32 + i * 16;  // block-local tile base
    const int da = eds[ebl + l15], sa = ess[ebl + l15];

    // A-frag of h1 = relu(P[dst] + Q[src] + b_in); 16B bf16 gathers
    union { short8 v; ushort_t u[8]; } a1[2];
#pragma unroll
    for (int c = 0; c < 2; c++) {
      const int col = c * 32 + quad * 8;
      union { ushort8 v; ushort_t u[8]; } pv, qv;
      pv.v = *(const ushort8*)&PQb[(u64)da * 128 + col];
      qv.v = *(const ushort8*)&PQb[(u64)sa * 128 + 64 + col];
      float4 bi0 = *(const float4*)(b_in + col);
      float4 bi1 = *(const float4*)(b_in + col + 4);
      a1[c].u[0] = f2bf(fmaxf(bf2f(pv.u[0]) + bf2f(qv.u[0]) + bi0.x, 0.f));
      a1[c].u[1] = f2bf(fmaxf(bf2f(pv.u[1]) + bf2f(qv.u[1]) + bi0.y, 0.f));
      a1[c].u[2] = f2bf(fmaxf(bf2f(pv.u[2]) + bf2f(qv.u[2]) + bi0.z, 0.f));
      a1[c].u[3] = f2bf(fmaxf(bf2f(pv.u[3]) + bf2f(qv.u[3]) + bi0.w, 0.f));
      a1[c].u[4] = f2bf(fmaxf(bf2f(pv.u[4]) + bf2f(qv.u[4]) + bi1.x, 0.f));
      a1[c].u[5] = f2bf(fmaxf(bf2f(pv.u[5]) + bf2f(qv.u[5]) + bi1.y, 0.f));
      a1[c].u[6] = f2bf(fmaxf(bf2f(pv.u[6]) + bf2f(qv.u[6]) + bi1.z, 0.f));
      a1[c].u[7] = f2bf(fmaxf(bf2f(pv.u[7]) + bf2f(qv.u[7]) + bi1.w, 0.f));
    }

    // h2 = relu(h1 @ Wh + b_h)
    f32x4 acc1[4];
#pragma unroll
    for (int nt = 0; nt < 4; nt++) {
      f32x4 acc = {0.f, 0.f, 0.f, 0.f};
#pragma unroll
      for (int c = 0; c < 2; c++) {
        short8 b = *(const short8*)&WhB[((nt * 2 + c) * 64 + lane) * 8];
        acc = __builtin_amdgcn_mfma_f32_16x16x32_bf16(a1[c].v, b, acc, 0, 0, 0);
      }
      acc1[nt] = acc;
    }
    // D-layout -> row-major LDS (wave-private; same-wave RAW via lgkmcnt)
    ushort_t* hb = h2s[wv * 2 + i];
#pragma unroll
    for (int nt = 0; nt < 4; nt++)
#pragma unroll
      for (int r = 0; r < 4; r++)
        hb[(quad * 4 + r) * 72 + nt * 16 + l15] =
            f2bf(fmaxf(acc1[nt][r] + bh[nt], 0.f));

    union { short8 v; ushort_t u[8]; } a2[2];
#pragma unroll
    for (int c = 0; c < 2; c++)
      a2[c].v = *(const short8*)&hb[l15 * 72 + c * 32 + quad * 8];

    // m = relu(h2 @ Wout + b_out)
    f32x4 acc2[8];
#pragma unroll
    for (int nt = 0; nt < 8; nt++) {
      f32x4 acc = {0.f, 0.f, 0.f, 0.f};
#pragma unroll
      for (int c = 0; c < 2; c++) {
        short8 b = *(const short8*)&WoB[((nt * 2 + c) * 64 + lane) * 8];
        acc = __builtin_amdgcn_mfma_f32_16x16x32_bf16(a2[c].v, b, acc, 0, 0, 0);
      }
      acc2[nt] = acc;
    }

    // stream out packed bf16 (cols 32k+l15 | 32k+16+l15), coalesced, no atomics
#pragma unroll
    for (int r = 0; r < 4; r++) {
      long long e = e0 + ebl + quad * 4 + r;
      if (e < NE) {
        unsigned* row = m_buf + (u64)e * 64;
#pragma unroll
        for (int k = 0; k < 4; k++) {
          float lo = fmaxf(acc2[2 * k][r] + bo[2 * k], 0.f);
          float hi = fmaxf(acc2[2 * k + 1][r] + bo[2 * k + 1], 0.f);
          row[k * 16 + l15] = (unsigned)f2bf(lo) | ((unsigned)f2bf(hi) << 16);
        }
      }
    }
  }
}

// ---- fused dst aggregation + projection: PQb' = bf16((sum m) @ W') --------
// Block owns 64 dsts; wave wv aggregates dsts [n0+wv*16, +16) from CSR rows
// (unroll-4) into a wave-private bf16 LDS A-tile, then MFMA -> PQb.
__global__ __launch_bounds__(256) void agg_proj(
    const unsigned* __restrict__ m_buf, const int* __restrict__ row_ptr,
    const ushort_t* __restrict__ WpB, ushort_t* __restrict__ PQb) {
  __shared__ ushort_t a_s[64 * 136];  // 64 rows x 128 bf16, pitch 136
  const int t = threadIdx.x;
  const int lane = t & 63, wv = t >> 6, quad = lane >> 4, l15 = lane & 15;
  const int n0 = blockIdx.x * 64;

  // phase 1: aggregate 16 rows (lane = packed col-dword: cols 32q+l15 / +16)
  for (int r = 0; r < 16; r++) {
    const int d = n0 + wv * 16 + r;
    float s0 = 0.f, s1 = 0.f;
    if (d < NA) {
      int beg = row_ptr[d], end = row_ptr[d + 1];
      float t0 = 0.f, t1 = 0.f, u0 = 0.f, u1 = 0.f, v0 = 0.f, v1 = 0.f;
      int e = beg;
      for (; e + 4 <= end; e += 4) {
        unsigned w0 = m_buf[(u64)(e + 0) * 64 + lane];
        unsigned w1 = m_buf[(u64)(e + 1) * 64 + lane];
        unsigned w2 = m_buf[(u64)(e + 2) * 64 + lane];
        unsigned w3 = m_buf[(u64)(e + 3) * 64 + lane];
        s0 += bf2f(w0 & 0xffffu); s1 += bf2f(w0 >> 16);
        t0 += bf2f(w1 & 0xffffu); t1 += bf2f(w1 >> 16);
        u0 += bf2f(w2 & 0xffffu); u1 += bf2f(w2 >> 16);
        v0 += bf2f(w3 & 0xffffu); v1 += bf2f(w3 >> 16);
      }
      for (; e < end; e++) {
        unsigned w0 = m_buf[(u64)e * 64 + lane];
        s0 += bf2f(w0 & 0xffffu); s1 += bf2f(w0 >> 16);
      }
      s0 = (s0 + t0) + (u0 + v0);
      s1 = (s1 + t1) + (u1 + v1);
    }
    const int row = wv * 16 + r;
    a_s[row * 136 + quad * 32 + l15] = f2bf(s0);
    a_s[row * 136 + quad * 32 + 16 + l15] = f2bf(s1);
  }
  // wave-private tile: same-wave LDS RAW ordered by lgkmcnt, no barrier

  // phase 2: PQ tile = A @ W' (A-frag from LDS)
  short8 a[4];
#pragma unroll
  for (int c = 0; c < 4; c++)
    a[c] = *(const short8*)&a_s[(wv * 16 + l15) * 136 + c * 32 + quad * 8];
#pragma unroll
  for (int nt = 0; nt < 8; nt++) {
    f32x4 acc = {0.f, 0.f, 0.f, 0.f};
#pragma unroll
    for (int c = 0; c < 4; c++) {
      short8 b = *(const short8*)&WpB[((nt * 4 + c) * 64 + lane) * 8];
      acc = __builtin_amdgcn_mfma_f32_16x16x32_bf16(a[c], b, acc, 0, 0, 0);
    }
#pragma unroll
    for (int r = 0; r < 4; r++) {
      int nn = n0 + wv * 16 + quad * 4 + r;
      if (nn < NA) PQb[(u64)nn * 128 + nt * 16 + l15] = f2bf(acc[r]);
    }
  }
}

// -------- final-step dst aggregation: wave per dst, unroll-4, no atomics ---
__global__ __launch_bounds__(256) void agg_dst(const unsigned* __restrict__ m_buf,
                                               const int* __restrict__ row_ptr,
                                               float* __restrict__ s_next) {
  int w = (blockIdx.x * 256 + threadIdx.x) >> 6;  // dst id
  int lane = threadIdx.x & 63;
  if (w >= NA) return;
  int beg = row_ptr[w], end = row_ptr[w + 1];
  float s0 = 0.f, s1 = 0.f, t0 = 0.f, t1 = 0.f, u0 = 0.f, u1 = 0.f, v0 = 0.f, v1 = 0.f;
  int e = beg;
  for (; e + 4 <= end; e += 4) {
    unsigned w0 = m_buf[(u64)(e + 0) * 64 + lane];
    unsigned w1 = m_buf[(u64)(e + 1) * 64 + lane];
    unsigned w2 = m_buf[(u64)(e + 2) * 64 + lane];
    unsigned w3 = m_buf[(u64)(e + 3) * 64 + lane];
    s0 += bf2f(w0 & 0xffffu); s1 += bf2f(w0 >> 16);
    t0 += bf2f(w1 & 0xffffu); t1 += bf2f(w1 >> 16);
    u0 += bf2f(w2 & 0xffffu); u1 += bf2f(w2 >> 16);
    v0 += bf2f(w3 & 0xffffu); v1 += bf2f(w3 >> 16);
  }
  for (; e < end; e++) {
    unsigned w0 = m_buf[(u64)e * 64 + lane];
    s0 += bf2f(w0 & 0xffffu); s1 += bf2f(w0 >> 16);
  }
  s0 = (s0 + t0) + (u0 + v0);
  s1 = (s1 + t1) + (u1 + v1);
  int k = lane >> 4, l15 = lane & 15;
  s_next[(u64)w * 128 + k * 32 + l15] = s0;
  s_next[(u64)w * 128 + k * 32 + 16 + l15] = s1;
}

// ------- molecule aggregation: chunked segmented sum over mol_sorted -------
__global__ __launch_bounds__(128) void agg_mol(const float* __restrict__ s_fin,
                                               const int* __restrict__ mol_sorted,
                                               const int* __restrict__ mol_ids,
                                               float* __restrict__ mol_repr) {
  __shared__ int rows[128], mids[128];
  const int c = threadIdx.x;
  const int base = blockIdx.x * 128;
  int n = NA - base; if (n > 128) n = 128;
  if (c < n) {
    int r = mol_sorted[base + c];
    rows[c] = r;
    mids[c] = mol_ids[r];
  }
  __syncthreads();
  float run = 0.f;
  int prev = mids[0];
#pragma unroll 4
  for (int i = 0; i < n; i++) {
    int m = mids[i];
    if (m != prev) {
      atomicAdd(&mol_repr[(u64)prev * 128 + c], run);
      run = 0.f; prev = m;
    }
    run += s_fin[(u64)rows[i] * 128 + c];
  }
  atomicAdd(&mol_repr[(u64)prev * 128 + c], run);
}

// ---------------- final tiny MLP per molecule ----------------
__global__ void final_mlp(const float* __restrict__ mol_repr,
                          const float* __restrict__ fc1_w, const float* __restrict__ fc1_b,
                          const float* __restrict__ fc2_w, const float* __restrict__ fc2_b,
                          const float* __restrict__ out_w, const float* __restrict__ out_b,
                          float* __restrict__ out) {
  int m = blockIdx.x, j = threadIdx.x;
  __shared__ float h1sh[64], h2sh[64];
  const float* mr = mol_repr + (u64)m * DF;
  float acc = fc1_b[j];
  for (int d = 0; d < DF; d++) acc = fmaf(mr[d], fc1_w[d * 64 + j], acc);
  h1sh[j] = fmaxf(acc, 0.f);
  __syncthreads();
  acc = fc2_b[j];
  for (int k = 0; k < 64; k++) acc = fmaf(h1sh[k], fc2_w[k * 64 + j], acc);
  h2sh[j] = fmaxf(acc, 0.f);
  __syncthreads();
  if (j < NOUT) {
    acc = out_b[j];
    for (int k = 0; k < 64; k++) acc = fmaf(h2sh[k], out_w[k * NOUT + j], acc);
    out[(u64)m * NOUT + j] = acc;
  }
}

extern "C" void kernel_launch(void* const* d_in, const int* in_sizes, int n_in,
                              void* d_out, int out_size, void* d_ws, size_t ws_size,
                              hipStream_t stream) {
  const float* states = (const float*)d_in[0];
  const float* Win    = (const float*)d_in[1];
  const float* b_in   = (const float*)d_in[2];
  const float* Wh     = (const float*)d_in[3];
  const float* b_h    = (const float*)d_in[4];
  const float* Wout   = (const float*)d_in[5];
  const float* b_out  = (const float*)d_in[6];
  const float* fc1_w  = (const float*)d_in[7];
  const float* fc1_b  = (const float*)d_in[8];
  const float* fc2_w  = (const float*)d_in[9];
  const float* fc2_b  = (const float*)d_in[10];
  const float* out_w  = (const float*)d_in[11];
  const float* out_b  = (const float*)d_in[12];
  const int* src      = (const int*)d_in[13];
  const int* dst      = (const int*)d_in[14];
  const int* mol_ids  = (const int*)d_in[15];

  char* ws = (char*)d_ws;
  u64 o = 0;
  auto alloc = [&](u64 bytes) {
    void* p = ws + o;
    o += (bytes + 255) & ~255ull;
    return p;
  };
  unsigned* m_buf = (unsigned*)alloc((u64)NE * 64 * 4);   // 102.4 MB
  ushort_t* PQb  = (ushort_t*)alloc((u64)NA * DF * 2);
  float* sA      = (float*)alloc((u64)NA * DF * 4);
  ushort_t* WpB  = (ushort_t*)alloc(3 * 16384 * 2);
  ushort_t* WhB  = (ushort_t*)alloc(3 * 4096 * 2);
  ushort_t* WoB  = (ushort_t*)alloc(3 * 8192 * 2);
  // zero-init block (single memset)
  char* zbase    = ws + o;
  float* molr    = (float*)alloc((u64)NMOL * DF * 4);
  int* counts    = (int*)alloc((u64)NA * 4);
  int* cursor    = (int*)alloc((u64)NA * 4);
  int* mcnt      = (int*)alloc(NMOL * 4);
  int* mcur      = (int*)alloc(NMOL * 4);
  u64 zbytes     = (u64)((ws + o) - zbase);
  int* row_ptr   = (int*)alloc((u64)(NA + 1) * 4);
  int* mrow      = (int*)alloc((NMOL + 1) * 4);
  int* dst_s     = (int*)alloc((u64)NE * 4);
  int* src_s     = (int*)alloc((u64)NE * 4);
  int* mol_sorted = (int*)alloc((u64)NA * 4);
  int* scan_tmp  = (int*)alloc((u64)NA * 4);
  int* blk_sums  = (int*)alloc(64 * 4);
  (void)ws_size; (void)in_sizes; (void)n_in; (void)out_size;

  const int NSCAN = (NA + 1023) / 1024;  // 49

  hipMemsetAsync(zbase, 0, zbytes, stream);

  setup_a<<<(NE + 255) / 256, 256, 0, stream>>>(Win, Wh, Wout, WpB, WhB, WoB,
                                                dst, mol_ids, counts, mcnt);
  scan_phase1<<<NSCAN, 1024, 0, stream>>>(counts, scan_tmp, blk_sums);
  scan_p2m<<<1, 256, 0, stream>>>(blk_sums, NSCAN, mcnt, mrow);
  scan_phase3<<<NSCAN, 1024, 0, stream>>>(scan_tmp, blk_sums, row_ptr);
  fill_ab<<<(NE + 255) / 256, 256, 0, stream>>>(src, dst, row_ptr, cursor, dst_s, src_s,
                                                mol_ids, mrow, mcur, mol_sorted);

  node_proj<<<(NA + 63) / 64, 256, 0, stream>>>(states, WpB, PQb);
  for (int t = 0; t < NSTEP; t++) {
    edge_msg<<<(NE + 127) / 128, 256, 0, stream>>>(
        PQb, WhB + t * 4096, WoB + t * 8192,
        b_in + t * 64, b_h + t * 64, b_out + t * 128, dst_s, src_s, m_buf);
    if (t < NSTEP - 1) {
      agg_proj<<<(NA + 63) / 64, 256, 0, stream>>>(m_buf, row_ptr,
                                                   WpB + (t + 1) * 16384, PQb);
    } else {
      agg_dst<<<(NA * 64 + 255) / 256, 256, 0, stream>>>(m_buf, row_ptr, sA);
    }
  }
  agg_mol<<<(NA + 127) / 128, 128, 0, stream>>>(sA, mol_sorted, mol_ids, molr);
  final_mlp<<<NMOL, 64, 0, stream>>>(molr, fc1_w, fc1_b, fc2_w, fc2_b, out_w, out_b,
                                     (float*)d_out);
}

// Round 9
// 447.909 us; speedup vs baseline: 1.4735x; 1.0455x over previous
//
#include <hip/hip_runtime.h>

typedef unsigned long long u64;
typedef unsigned short ushort_t;

#define NA 50000
#define NE 400000
#define DF 128
#define HID 64
#define NMOL 256
#define NOUT 32
#define NSTEP 3

typedef __attribute__((ext_vector_type(8))) short short8;
typedef __attribute__((ext_vector_type(8))) unsigned short ushort8;
typedef __attribute__((ext_vector_type(4))) float f32x4;

static __device__ __forceinline__ ushort_t f2bf(float f) {
  union { float f; unsigned u; } v; v.f = f;
  unsigned r = v.u + 0x7fffu + ((v.u >> 16) & 1u);
  return (ushort_t)(r >> 16);
}
static __device__ __forceinline__ float bf2f(unsigned b) {
  union { unsigned u; float f; } v; v.u = b << 16;
  return v.f;
}

// -------- fused setup: pack weights (B-frag order) + degree histograms -----
__global__ void setup_a(const float* __restrict__ Win, const float* __restrict__ Wh,
                        const float* __restrict__ Wout,
                        ushort_t* __restrict__ WpB, ushort_t* __restrict__ WhB,
                        ushort_t* __restrict__ WoB,
                        const int* __restrict__ dst, const int* __restrict__ mol_ids,
                        int* __restrict__ counts, int* __restrict__ mcnt) {
  int g = blockIdx.x * 256 + threadIdx.x;
  if (g < 3 * 16384) {
    int tt = g / 16384, r = g % 16384;
    int j = r & 7, lane = (r >> 3) & 63, f = r >> 9;
    int kc = f & 3, nt = f >> 2;
    int k = kc * 32 + (lane >> 4) * 8 + j;
    int n = nt * 16 + (lane & 15);
    float v = (n < 64) ? Win[tt * 16384 + k * 64 + n]
                       : Win[tt * 16384 + (128 + k) * 64 + (n - 64)];
    WpB[g] = f2bf(v);
  }
  int g2 = g - 3 * 16384;
  if (g2 >= 0 && g2 < 3 * 4096) {
    int tt = g2 / 4096, r = g2 % 4096;
    int j = r & 7, lane = (r >> 3) & 63, f = r >> 9;
    int kc = f & 1, nt = f >> 1;
    int k = kc * 32 + (lane >> 4) * 8 + j;
    int n = nt * 16 + (lane & 15);
    WhB[g2] = f2bf(Wh[tt * 4096 + k * 64 + n]);
  }
  int g3 = g2 - 3 * 4096;
  if (g3 >= 0 && g3 < 3 * 8192) {
    int tt = g3 / 8192, r = g3 % 8192;
    int j = r & 7, lane = (r >> 3) & 63, f = r >> 9;
    int kc = f & 1, nt = f >> 1;
    int k = kc * 32 + (lane >> 4) * 8 + j;
    int n = nt * 16 + (lane & 15);
    WoB[g3] = f2bf(Wout[tt * 8192 + k * 128 + n]);
  }
  if (g < NE) atomicAdd(&counts[dst[g]], 1);
  if (g < NA) atomicAdd(&mcnt[mol_ids[g]], 1);
}

__global__ void scan_phase1(const int* __restrict__ counts, int* __restrict__ tmp,
                            int* __restrict__ blk) {
  __shared__ int sh[1024];
  int t = threadIdx.x;
  int i = blockIdx.x * 1024 + t;
  sh[t] = (i < NA) ? counts[i] : 0;
  __syncthreads();
  for (int off = 1; off < 1024; off <<= 1) {
    int x = (t >= off) ? sh[t - off] : 0;
    __syncthreads();
    sh[t] += x;
    __syncthreads();
  }
  if (i < NA) tmp[i] = sh[t];
  if (t == 1023) blk[blockIdx.x] = sh[1023];
}

__global__ void scan_p2m(int* __restrict__ blk, int nblk,
                         const int* __restrict__ mcnt, int* __restrict__ mrow) {
  __shared__ int sh[64];
  __shared__ int ms[NMOL];
  int t = threadIdx.x;
  if (t < 64) sh[t] = (t < nblk) ? blk[t] : 0;
  ms[t] = mcnt[t];
  __syncthreads();
  if (t == 0) {
    int run = 0;
    for (int k = 0; k < nblk; k++) { int c = sh[k]; sh[k] = run; run += c; }
  }
  for (int off = 1; off < NMOL; off <<= 1) {
    int x = (t >= off) ? ms[t - off] : 0;
    __syncthreads();
    ms[t] += x;
    __syncthreads();
  }
  if (t < nblk) blk[t] = sh[t];
  mrow[t + 1] = ms[t];
  if (t == 0) mrow[0] = 0;
}

__global__ void scan_phase3(const int* __restrict__ tmp, const int* __restrict__ blk,
                            int* __restrict__ row_ptr) {
  int i = blockIdx.x * 1024 + threadIdx.x;
  if (i < NA) row_ptr[i + 1] = tmp[i] + blk[blockIdx.x];
  if (i == 0 && blockIdx.x == 0) row_ptr[0] = 0;
}

__global__ void fill_ab(const int* __restrict__ src, const int* __restrict__ dst,
                        const int* __restrict__ row_ptr, int* __restrict__ cursor,
                        int* __restrict__ dst_s, int* __restrict__ src_s,
                        const int* __restrict__ mol_ids, const int* __restrict__ mrow,
                        int* __restrict__ mcur, int* __restrict__ mol_sorted) {
  int e = blockIdx.x * 256 + threadIdx.x;
  if (e < NE) {
    int d = dst[e];
    int pos = row_ptr[d] + atomicAdd(&cursor[d], 1);
    dst_s[pos] = d;
    src_s[pos] = src[e];
  }
  if (e < NA) {
    int m = mol_ids[e];
    int pos = mrow[m] + atomicAdd(&mcur[m], 1);
    mol_sorted[pos] = e;
  }
}

// ---- sub-run scan: opos[e] = index of e's sub-run (4-edge-window x dst) ----
__global__ void escan_p1(const int* __restrict__ dst_s, int* __restrict__ etmp,
                         int* __restrict__ eblk) {
  __shared__ int sh[1024];
  int t = threadIdx.x;
  int i = blockIdx.x * 1024 + t;
  int f = 0;
  if (i < NE) f = ((i & 3) == 0 || dst_s[i] != dst_s[i - 1]) ? 1 : 0;
  sh[t] = f;
  __syncthreads();
  for (int off = 1; off < 1024; off <<= 1) {
    int x = (t >= off) ? sh[t - off] : 0;
    __syncthreads();
    sh[t] += x;
    __syncthreads();
  }
  if (i < NE) etmp[i] = sh[t];
  if (t == 1023) eblk[blockIdx.x] = sh[1023];
}

__global__ void escan_p2(int* __restrict__ eblk, int nblk) {
  __shared__ int sh[512];
  int t = threadIdx.x;
  sh[t] = (t < nblk) ? eblk[t] : 0;
  __syncthreads();
  if (t == 0) {
    int run = 0;
    for (int k = 0; k < nblk; k++) { int c = sh[k]; sh[k] = run; run += c; }
  }
  __syncthreads();
  if (t < nblk) eblk[t] = sh[t];
}

__global__ void escan_p3(const int* __restrict__ etmp, const int* __restrict__ eblk,
                         int* __restrict__ opos) {
  int i = blockIdx.x * 1024 + threadIdx.x;
  if (i < NE) {
    int v = etmp[i] + eblk[blockIdx.x] - 1;
    opos[i] = v;
    if (i == NE - 1) opos[NE] = v + 1;
  }
}

// ---------------- node projection: PQb = bf16(s @ W')  (MFMA, LDS-free) ----
__global__ __launch_bounds__(256) void node_proj(const float* __restrict__ s_in,
                                                 const ushort_t* __restrict__ WpB,
                                                 ushort_t* __restrict__ PQb) {
  const int t = threadIdx.x;
  const int lane = t & 63, wv = t >> 6, quad = lane >> 4, l15 = lane & 15;
  const int n0 = blockIdx.x * 64 + wv * 16;
  int n = n0 + l15; if (n >= NA) n = NA - 1;
  union { short8 v; ushort_t u[8]; } a[4];
#pragma unroll
  for (int c = 0; c < 4; c++) {
    const float* p = s_in + (u64)n * 128 + c * 32 + quad * 8;
    float4 f0 = *(const float4*)(p);
    float4 f1 = *(const float4*)(p + 4);
    a[c].u[0] = f2bf(f0.x); a[c].u[1] = f2bf(f0.y);
    a[c].u[2] = f2bf(f0.z); a[c].u[3] = f2bf(f0.w);
    a[c].u[4] = f2bf(f1.x); a[c].u[5] = f2bf(f1.y);
    a[c].u[6] = f2bf(f1.z); a[c].u[7] = f2bf(f1.w);
  }
#pragma unroll
  for (int nt = 0; nt < 8; nt++) {
    f32x4 acc = {0.f, 0.f, 0.f, 0.f};
#pragma unroll
    for (int c = 0; c < 4; c++) {
      short8 b = *(const short8*)&WpB[((nt * 4 + c) * 64 + lane) * 8];
      acc = __builtin_amdgcn_mfma_f32_16x16x32_bf16(a[c].v, b, acc, 0, 0, 0);
    }
#pragma unroll
    for (int r = 0; r < 4; r++) {
      int nn = n0 + quad * 4 + r;
      if (nn < NA) PQb[(u64)nn * 128 + nt * 16 + l15] = f2bf(acc[r]);
    }
  }
}

// ------ fused edge MLP (MFMA) -> packed-bf16 SUB-RUN partial sums ----------
// 128 edges / workgroup. Each lane-quad owns 4 sorted edges; segments them by
// dst and writes one fp32-accumulated partial row per sub-run (plain stores,
// each sub-run owned by exactly one quad). NE % 128 == 0: no padding.
__global__ __launch_bounds__(256) void edge_msg(
    const ushort_t* __restrict__ PQb,
    const ushort_t* __restrict__ WhB, const ushort_t* __restrict__ WoB,
    const float* __restrict__ b_in, const float* __restrict__ b_h,
    const float* __restrict__ b_out,
    const int* __restrict__ dst_s, const int* __restrict__ src_s,
    const int* __restrict__ opos,
    unsigned* __restrict__ m_buf) {
  __shared__ int eds[128], ess[128], ops[128];
  __shared__ ushort_t h2s[8][16 * 72];  // per-(wave,i) 16 x 64 bf16, pitch 72
  const int t = threadIdx.x;
  const int lane = t & 63, wv = t >> 6, quad = lane >> 4, l15 = lane & 15;
  const long long e0 = (long long)blockIdx.x * 128;

  if (t < 128) {
    long long e = e0 + t;
    eds[t] = dst_s[e]; ess[t] = src_s[e]; ops[t] = opos[e];
  }
  float bh[4], bo[8];
#pragma unroll
  for (int nt = 0; nt < 4; nt++) bh[nt] = b_h[nt * 16 + l15];
#pragma unroll
  for (int nt = 0; nt < 8; nt++) bo[nt] = b_out[nt * 16 + l15];
  __syncthreads();

#pragma unroll
  for (int i = 0; i < 2; i++) {
    const int ebl = wv * 32 + i * 16;  // block-local tile base
    const int da = eds[ebl + l15], sa = ess[ebl + l15];

    // A-frag of h1 = relu(P[dst] + Q[src] + b_in); 16B bf16 gathers
    union { short8 v; ushort_t u[8]; } a1[2];
#pragma unroll
    for (int c = 0; c < 2; c++) {
      const int col = c * 32 + quad * 8;
      union { ushort8 v; ushort_t u[8]; } pv, qv;
      pv.v = *(const ushort8*)&PQb[(u64)da * 128 + col];
      qv.v = *(const ushort8*)&PQb[(u64)sa * 128 + 64 + col];
      float4 bi0 = *(const float4*)(b_in + col);
      float4 bi1 = *(const float4*)(b_in + col + 4);
      a1[c].u[0] = f2bf(fmaxf(bf2f(pv.u[0]) + bf2f(qv.u[0]) + bi0.x, 0.f));
      a1[c].u[1] = f2bf(fmaxf(bf2f(pv.u[1]) + bf2f(qv.u[1]) + bi0.y, 0.f));
      a1[c].u[2] = f2bf(fmaxf(bf2f(pv.u[2]) + bf2f(qv.u[2]) + bi0.z, 0.f));
      a1[c].u[3] = f2bf(fmaxf(bf2f(pv.u[3]) + bf2f(qv.u[3]) + bi0.w, 0.f));
      a1[c].u[4] = f2bf(fmaxf(bf2f(pv.u[4]) + bf2f(qv.u[4]) + bi1.x, 0.f));
      a1[c].u[5] = f2bf(fmaxf(bf2f(pv.u[5]) + bf2f(qv.u[5]) + bi1.y, 0.f));
      a1[c].u[6] = f2bf(fmaxf(bf2f(pv.u[6]) + bf2f(qv.u[6]) + bi1.z, 0.f));
      a1[c].u[7] = f2bf(fmaxf(bf2f(pv.u[7]) + bf2f(qv.u[7]) + bi1.w, 0.f));
    }

    // h2 = relu(h1 @ Wh + b_h)
    f32x4 acc1[4];
#pragma unroll
    for (int nt = 0; nt < 4; nt++) {
      f32x4 acc = {0.f, 0.f, 0.f, 0.f};
#pragma unroll
      for (int c = 0; c < 2; c++) {
        short8 b = *(const short8*)&WhB[((nt * 2 + c) * 64 + lane) * 8];
        acc = __builtin_amdgcn_mfma_f32_16x16x32_bf16(a1[c].v, b, acc, 0, 0, 0);
      }
      acc1[nt] = acc;
    }
    // D-layout -> row-major LDS (wave-private; same-wave RAW via lgkmcnt)
    ushort_t* hb = h2s[wv * 2 + i];
#pragma unroll
    for (int nt = 0; nt < 4; nt++)
#pragma unroll
      for (int r = 0; r < 4; r++)
        hb[(quad * 4 + r) * 72 + nt * 16 + l15] =
            f2bf(fmaxf(acc1[nt][r] + bh[nt], 0.f));

    union { short8 v; ushort_t u[8]; } a2[2];
#pragma unroll
    for (int c = 0; c < 2; c++)
      a2[c].v = *(const short8*)&hb[l15 * 72 + c * 32 + quad * 8];

    // m = relu(h2 @ Wout + b_out)
    f32x4 acc2[8];
#pragma unroll
    for (int nt = 0; nt < 8; nt++) {
      f32x4 acc = {0.f, 0.f, 0.f, 0.f};
#pragma unroll
      for (int c = 0; c < 2; c++) {
        short8 b = *(const short8*)&WoB[((nt * 2 + c) * 64 + lane) * 8];
        acc = __builtin_amdgcn_mfma_f32_16x16x32_bf16(a2[c].v, b, acc, 0, 0, 0);
      }
      acc2[nt] = acc;
    }

    // segmented sub-run flush: fp32 partials over the quad's 4 edges
    {
      const int base = ebl + quad * 4;
      int prev = eds[base];
      int orow = ops[base];
      float run[8];
#pragma unroll
      for (int nt = 0; nt < 8; nt++) run[nt] = 0.f;
#pragma unroll
      for (int r = 0; r < 4; r++) {
        int er = base + r;
        if (eds[er] != prev) {
          unsigned* rowp = m_buf + (u64)orow * 64;
#pragma unroll
          for (int k = 0; k < 4; k++)
            rowp[k * 16 + l15] =
                (unsigned)f2bf(run[2 * k]) | ((unsigned)f2bf(run[2 * k + 1]) << 16);
#pragma unroll
          for (int nt = 0; nt < 8; nt++) run[nt] = 0.f;
          prev = eds[er]; orow = ops[er];
        }
#pragma unroll
        for (int nt = 0; nt < 8; nt++)
          run[nt] += fmaxf(acc2[nt][r] + bo[nt], 0.f);
      }
      unsigned* rowp = m_buf + (u64)orow * 64;
#pragma unroll
      for (int k = 0; k < 4; k++)
        rowp[k * 16 + l15] =
            (unsigned)f2bf(run[2 * k]) | ((unsigned)f2bf(run[2 * k + 1]) << 16);
    }
  }
}

// ---- fused dst aggregation + projection over sub-run CSR ------------------
__global__ __launch_bounds__(256) void agg_proj(
    const unsigned* __restrict__ m_buf, const int* __restrict__ row_ptr,
    const int* __restrict__ opos,
    const ushort_t* __restrict__ WpB, ushort_t* __restrict__ PQb) {
  __shared__ ushort_t a_s[64 * 136];  // 64 rows x 128 bf16, pitch 136
  const int t = threadIdx.x;
  const int lane = t & 63, wv = t >> 6, quad = lane >> 4, l15 = lane & 15;
  const int n0 = blockIdx.x * 64;

  // phase 1: aggregate 16 dsts' sub-runs (lane = packed col-dword)
  for (int r = 0; r < 16; r++) {
    const int d = n0 + wv * 16 + r;
    float s0 = 0.f, s1 = 0.f;
    if (d < NA) {
      int ob = opos[row_ptr[d]], oe = opos[row_ptr[d + 1]];
      int n = oe - ob;
      float t0 = 0.f, t1 = 0.f, u0 = 0.f, u1 = 0.f, v0 = 0.f, v1 = 0.f;
      int full = n & ~3;
      int e = ob;
      for (; e < ob + full; e += 4) {
        unsigned w0 = m_buf[(u64)(e + 0) * 64 + lane];
        unsigned w1 = m_buf[(u64)(e + 1) * 64 + lane];
        unsigned w2 = m_buf[(u64)(e + 2) * 64 + lane];
        unsigned w3 = m_buf[(u64)(e + 3) * 64 + lane];
        s0 += bf2f(w0 & 0xffffu); s1 += bf2f(w0 >> 16);
        t0 += bf2f(w1 & 0xffffu); t1 += bf2f(w1 >> 16);
        u0 += bf2f(w2 & 0xffffu); u1 += bf2f(w2 >> 16);
        v0 += bf2f(w3 & 0xffffu); v1 += bf2f(w3 >> 16);
      }
      int rem = n - full;
      if (rem > 0) {  // wave-uniform; all tail loads issue together
        int i1 = (rem > 1) ? e + 1 : e;
        int i2 = (rem > 2) ? e + 2 : e;
        unsigned w0 = m_buf[(u64)e * 64 + lane];
        unsigned w1 = m_buf[(u64)i1 * 64 + lane];
        unsigned w2 = m_buf[(u64)i2 * 64 + lane];
        s0 += bf2f(w0 & 0xffffu); s1 += bf2f(w0 >> 16);
        if (rem > 1) { t0 += bf2f(w1 & 0xffffu); t1 += bf2f(w1 >> 16); }
        if (rem > 2) { u0 += bf2f(w2 & 0xffffu); u1 += bf2f(w2 >> 16); }
      }
      s0 = (s0 + t0) + (u0 + v0);
      s1 = (s1 + t1) + (u1 + v1);
    }
    const int row = wv * 16 + r;
    a_s[row * 136 + quad * 32 + l15] = f2bf(s0);
    a_s[row * 136 + quad * 32 + 16 + l15] = f2bf(s1);
  }
  // wave-private tile: same-wave LDS RAW ordered by lgkmcnt, no barrier

  // phase 2: PQ tile = A @ W' (A-frag from LDS)
  short8 a[4];
#pragma unroll
  for (int c = 0; c < 4; c++)
    a[c] = *(const short8*)&a_s[(wv * 16 + l15) * 136 + c * 32 + quad * 8];
#pragma unroll
  for (int nt = 0; nt < 8; nt++) {
    f32x4 acc = {0.f, 0.f, 0.f, 0.f};
#pragma unroll
    for (int c = 0; c < 4; c++) {
      short8 b = *(const short8*)&WpB[((nt * 4 + c) * 64 + lane) * 8];
      acc = __builtin_amdgcn_mfma_f32_16x16x32_bf16(a[c], b, acc, 0, 0, 0);
    }
#pragma unroll
    for (int r = 0; r < 4; r++) {
      int nn = n0 + wv * 16 + quad * 4 + r;
      if (nn < NA) PQb[(u64)nn * 128 + nt * 16 + l15] = f2bf(acc[r]);
    }
  }
}

// -------- final-step dst aggregation over sub-run CSR, no atomics ----------
__global__ __launch_bounds__(256) void agg_dst(const unsigned* __restrict__ m_buf,
                                               const int* __restrict__ row_ptr,
                                               const int* __restrict__ opos,
                                               float* __restrict__ s_next) {
  int w = (blockIdx.x * 256 + threadIdx.x) >> 6;  // dst id
  int lane = threadIdx.x & 63;
  if (w >= NA) return;
  int ob = opos[row_ptr[w]], oe = opos[row_ptr[w + 1]];
  int n = oe - ob;
  float s0 = 0.f, s1 = 0.f, t0 = 0.f, t1 = 0.f, u0 = 0.f, u1 = 0.f, v0 = 0.f, v1 = 0.f;
  int full = n & ~3;
  int e = ob;
  for (; e < ob + full; e += 4) {
    unsigned w0 = m_buf[(u64)(e + 0) * 64 + lane];
    unsigned w1 = m_buf[(u64)(e + 1) * 64 + lane];
    unsigned w2 = m_buf[(u64)(e + 2) * 64 + lane];
    unsigned w3 = m_buf[(u64)(e + 3) * 64 + lane];
    s0 += bf2f(w0 & 0xffffu); s1 += bf2f(w0 >> 16);
    t0 += bf2f(w1 & 0xffffu); t1 += bf2f(w1 >> 16);
    u0 += bf2f(w2 & 0xffffu); u1 += bf2f(w2 >> 16);
    v0 += bf2f(w3 & 0xffffu); v1 += bf2f(w3 >> 16);
  }
  int rem = n - full;
  if (rem > 0) {
    int i1 = (rem > 1) ? e + 1 : e;
    int i2 = (rem > 2) ? e + 2 : e;
    unsigned w0 = m_buf[(u64)e * 64 + lane];
    unsigned w1 = m_buf[(u64)i1 * 64 + lane];
    unsigned w2 = m_buf[(u64)i2 * 64 + lane];
    s0 += bf2f(w0 & 0xffffu); s1 += bf2f(w0 >> 16);
    if (rem > 1) { t0 += bf2f(w1 & 0xffffu); t1 += bf2f(w1 >> 16); }
    if (rem > 2) { u0 += bf2f(w2 & 0xffffu); u1 += bf2f(w2 >> 16); }
  }
  s0 = (s0 + t0) + (u0 + v0);
  s1 = (s1 + t1) + (u1 + v1);
  int k = lane >> 4, l15 = lane & 15;
  s_next[(u64)w * 128 + k * 32 + l15] = s0;
  s_next[(u64)w * 128 + k * 32 + 16 + l15] = s1;
}

// ------- molecule aggregation: chunked segmented sum over mol_sorted -------
__global__ __launch_bounds__(128) void agg_mol(const float* __restrict__ s_fin,
                                               const int* __restrict__ mol_sorted,
                                               const int* __restrict__ mol_ids,
                                               float* __restrict__ mol_repr) {
  __shared__ int rows[128], mids[128];
  const int c = threadIdx.x;
  const int base = blockIdx.x * 128;
  int n = NA - base; if (n > 128) n = 128;
  if (c < n) {
    int r = mol_sorted[base + c];
    rows[c] = r;
    mids[c] = mol_ids[r];
  }
  __syncthreads();
  float run = 0.f;
  int prev = mids[0];
#pragma unroll 4
  for (int i = 0; i < n; i++) {
    int m = mids[i];
    if (m != prev) {
      atomicAdd(&mol_repr[(u64)prev * 128 + c], run);
      run = 0.f; prev = m;
    }
    run += s_fin[(u64)rows[i] * 128 + c];
  }
  atomicAdd(&mol_repr[(u64)prev * 128 + c], run);
}

// ---------------- final tiny MLP per molecule ----------------
__global__ void final_mlp(const float* __restrict__ mol_repr,
                          const float* __restrict__ fc1_w, const float* __restrict__ fc1_b,
                          const float* __restrict__ fc2_w, const float* __restrict__ fc2_b,
                          const float* __restrict__ out_w, const float* __restrict__ out_b,
                          float* __restrict__ out) {
  int m = blockIdx.x, j = threadIdx.x;
  __shared__ float h1sh[64], h2sh[64];
  const float* mr = mol_repr + (u64)m * DF;
  float acc = fc1_b[j];
  for (int d = 0; d < DF; d++) acc = fmaf(mr[d], fc1_w[d * 64 + j], acc);
  h1sh[j] = fmaxf(acc, 0.f);
  __syncthreads();
  acc = fc2_b[j];
  for (int k = 0; k < 64; k++) acc = fmaf(h1sh[k], fc2_w[k * 64 + j], acc);
  h2sh[j] = fmaxf(acc, 0.f);
  __syncthreads();
  if (j < NOUT) {
    acc = out_b[j];
    for (int k = 0; k < 64; k++) acc = fmaf(h2sh[k], out_w[k * NOUT + j], acc);
    out[(u64)m * NOUT + j] = acc;
  }
}

extern "C" void kernel_launch(void* const* d_in, const int* in_sizes, int n_in,
                              void* d_out, int out_size, void* d_ws, size_t ws_size,
                              hipStream_t stream) {
  const float* states = (const float*)d_in[0];
  const float* Win    = (const float*)d_in[1];
  const float* b_in   = (const float*)d_in[2];
  const float* Wh     = (const float*)d_in[3];
  const float* b_h    = (const float*)d_in[4];
  const float* Wout   = (const float*)d_in[5];
  const float* b_out  = (const float*)d_in[6];
  const float* fc1_w  = (const float*)d_in[7];
  const float* fc1_b  = (const float*)d_in[8];
  const float* fc2_w  = (const float*)d_in[9];
  const float* fc2_b  = (const float*)d_in[10];
  const float* out_w  = (const float*)d_in[11];
  const float* out_b  = (const float*)d_in[12];
  const int* src      = (const int*)d_in[13];
  const int* dst      = (const int*)d_in[14];
  const int* mol_ids  = (const int*)d_in[15];

  char* ws = (char*)d_ws;
  u64 o = 0;
  auto alloc = [&](u64 bytes) {
    void* p = ws + o;
    o += (bytes + 255) & ~255ull;
    return p;
  };
  unsigned* m_buf = (unsigned*)alloc((u64)NE * 64 * 4);   // worst-case R = NE
  ushort_t* PQb  = (ushort_t*)alloc((u64)NA * DF * 2);
  float* sA      = (float*)alloc((u64)NA * DF * 4);
  ushort_t* WpB  = (ushort_t*)alloc(3 * 16384 * 2);
  ushort_t* WhB  = (ushort_t*)alloc(3 * 4096 * 2);
  ushort_t* WoB  = (ushort_t*)alloc(3 * 8192 * 2);
  // zero-init block (single memset)
  char* zbase    = ws + o;
  float* molr    = (float*)alloc((u64)NMOL * DF * 4);
  int* counts    = (int*)alloc((u64)NA * 4);
  int* cursor    = (int*)alloc((u64)NA * 4);
  int* mcnt      = (int*)alloc(NMOL * 4);
  int* mcur      = (int*)alloc(NMOL * 4);
  u64 zbytes     = (u64)((ws + o) - zbase);
  int* row_ptr   = (int*)alloc((u64)(NA + 1) * 4);
  int* mrow      = (int*)alloc((NMOL + 1) * 4);
  int* dst_s     = (int*)alloc((u64)NE * 4);
  int* src_s     = (int*)alloc((u64)NE * 4);
  int* mol_sorted = (int*)alloc((u64)NA * 4);
  int* scan_tmp  = (int*)alloc((u64)NA * 4);
  int* blk_sums  = (int*)alloc(64 * 4);
  int* opos      = (int*)alloc((u64)(NE + 1) * 4);
  int* etmp      = (int*)alloc((u64)NE * 4);
  int* eblk      = (int*)alloc(512 * 4);
  (void)ws_size; (void)in_sizes; (void)n_in; (void)out_size;

  const int NSCAN = (NA + 1023) / 1024;   // 49
  const int NESCAN = (NE + 1023) / 1024;  // 391

  hipMemsetAsync(zbase, 0, zbytes, stream);

  setup_a<<<(NE + 255) / 256, 256, 0, stream>>>(Win, Wh, Wout, WpB, WhB, WoB,
                                                dst, mol_ids, counts, mcnt);
  scan_phase1<<<NSCAN, 1024, 0, stream>>>(counts, scan_tmp, blk_sums);
  scan_p2m<<<1, 256, 0, stream>>>(blk_sums, NSCAN, mcnt, mrow);
  scan_phase3<<<NSCAN, 1024, 0, stream>>>(scan_tmp, blk_sums, row_ptr);
  fill_ab<<<(NE + 255) / 256, 256, 0, stream>>>(src, dst, row_ptr, cursor, dst_s, src_s,
                                                mol_ids, mrow, mcur, mol_sorted);
  escan_p1<<<NESCAN, 1024, 0, stream>>>(dst_s, etmp, eblk);
  escan_p2<<<1, 512, 0, stream>>>(eblk, NESCAN);
  escan_p3<<<NESCAN, 1024, 0, stream>>>(etmp, eblk, opos);

  node_proj<<<(NA + 63) / 64, 256, 0, stream>>>(states, WpB, PQb);
  for (int t = 0; t < NSTEP; t++) {
    edge_msg<<<(NE + 127) / 128, 256, 0, stream>>>(
        PQb, WhB + t * 4096, WoB + t * 8192,
        b_in + t * 64, b_h + t * 64, b_out + t * 128, dst_s, src_s, opos, m_buf);
    if (t < NSTEP - 1) {
      agg_proj<<<(NA + 63) / 64, 256, 0, stream>>>(m_buf, row_ptr, opos,
                                                   WpB + (t + 1) * 16384, PQb);
    } else {
      agg_dst<<<(NA * 64 + 255) / 256, 256, 0, stream>>>(m_buf, row_ptr, opos, sA);
    }
  }
  agg_mol<<<(NA + 127) / 128, 128, 0, stream>>>(sA, mol_sorted, mol_ids, molr);
  final_mlp<<<NMOL, 64, 0, stream>>>(molr, fc1_w, fc1_b, fc2_w, fc2_b, out_w, out_b,
                                     (float*)d_out);
}

// Round 10
// 431.435 us; speedup vs baseline: 1.5297x; 1.0382x over previous
//
#include <hip/hip_runtime.h>

typedef unsigned long long u64;
typedef unsigned short ushort_t;

#define NA 50000
#define NE 400000
#define DF 128
#define HID 64
#define NMOL 256
#define NOUT 32
#define NSTEP 3

typedef __attribute__((ext_vector_type(8))) short short8;
typedef __attribute__((ext_vector_type(8))) unsigned short ushort8;
typedef __attribute__((ext_vector_type(4))) float f32x4;

static __device__ __forceinline__ ushort_t f2bf(float f) {
  union { float f; unsigned u; } v; v.f = f;
  unsigned r = v.u + 0x7fffu + ((v.u >> 16) & 1u);
  return (ushort_t)(r >> 16);
}
static __device__ __forceinline__ float bf2f(unsigned b) {
  union { unsigned u; float f; } v; v.u = b << 16;
  return v.f;
}

// -------- fused setup: pack weights (B-frag order) + degree histograms -----
__global__ void setup_a(const float* __restrict__ Win, const float* __restrict__ Wh,
                        const float* __restrict__ Wout,
                        ushort_t* __restrict__ WpB, ushort_t* __restrict__ WhB,
                        ushort_t* __restrict__ WoB,
                        const int* __restrict__ dst, const int* __restrict__ mol_ids,
                        int* __restrict__ counts, int* __restrict__ mcnt) {
  int g = blockIdx.x * 256 + threadIdx.x;
  if (g < 3 * 16384) {
    int tt = g / 16384, r = g % 16384;
    int j = r & 7, lane = (r >> 3) & 63, f = r >> 9;
    int kc = f & 3, nt = f >> 2;
    int k = kc * 32 + (lane >> 4) * 8 + j;
    int n = nt * 16 + (lane & 15);
    float v = (n < 64) ? Win[tt * 16384 + k * 64 + n]
                       : Win[tt * 16384 + (128 + k) * 64 + (n - 64)];
    WpB[g] = f2bf(v);
  }
  int g2 = g - 3 * 16384;
  if (g2 >= 0 && g2 < 3 * 4096) {
    int tt = g2 / 4096, r = g2 % 4096;
    int j = r & 7, lane = (r >> 3) & 63, f = r >> 9;
    int kc = f & 1, nt = f >> 1;
    int k = kc * 32 + (lane >> 4) * 8 + j;
    int n = nt * 16 + (lane & 15);
    WhB[g2] = f2bf(Wh[tt * 4096 + k * 64 + n]);
  }
  int g3 = g2 - 3 * 4096;
  if (g3 >= 0 && g3 < 3 * 8192) {
    int tt = g3 / 8192, r = g3 % 8192;
    int j = r & 7, lane = (r >> 3) & 63, f = r >> 9;
    int kc = f & 1, nt = f >> 1;
    int k = kc * 32 + (lane >> 4) * 8 + j;
    int n = nt * 16 + (lane & 15);
    WoB[g3] = f2bf(Wout[tt * 8192 + k * 128 + n]);
  }
  if (g < NE) atomicAdd(&counts[dst[g]], 1);
  if (g < NA) atomicAdd(&mcnt[mol_ids[g]], 1);
}

// per-1024-block inclusive scan of counts; last block also scans mol histogram
__global__ void scan_phase1(const int* __restrict__ counts, int* __restrict__ tmp,
                            int* __restrict__ blk,
                            const int* __restrict__ mcnt, int* __restrict__ mrow) {
  __shared__ int sh[1024];
  int t = threadIdx.x;
  int i = blockIdx.x * 1024 + t;
  sh[t] = (i < NA) ? counts[i] : 0;
  __syncthreads();
  for (int off = 1; off < 1024; off <<= 1) {
    int x = (t >= off) ? sh[t - off] : 0;
    __syncthreads();
    sh[t] += x;
    __syncthreads();
  }
  if (i < NA) tmp[i] = sh[t];
  if (t == 1023) blk[blockIdx.x] = sh[1023];
  if (blockIdx.x == gridDim.x - 1) {  // fold in the molecule scan
    __syncthreads();
    sh[t] = (t < NMOL) ? mcnt[t] : 0;
    __syncthreads();
    for (int off = 1; off < NMOL; off <<= 1) {
      int x = (t >= off && t < NMOL) ? sh[t - off] : 0;
      __syncthreads();
      if (t < NMOL) sh[t] += x;
      __syncthreads();
    }
    if (t < NMOL) mrow[t + 1] = sh[t];
    if (t == 0) mrow[0] = 0;
  }
}

// row_ptr[i+1] = tmp[i] + prefix(blk, bid); prefix computed by wave-reduce
__global__ void scan_phase3(const int* __restrict__ tmp, const int* __restrict__ blk,
                            int* __restrict__ row_ptr) {
  __shared__ int spre_sh;
  int t = threadIdx.x;
  int bid = blockIdx.x;
  if (t < 64) {
    int v = (t < bid) ? blk[t] : 0;  // bid <= 48 < 64
    for (int off = 32; off; off >>= 1) v += __shfl_down(v, off);
    if (t == 0) spre_sh = v;
  }
  __syncthreads();
  int spre = spre_sh;
  int i = bid * 1024 + t;
  if (i < NA) row_ptr[i + 1] = tmp[i] + spre;
  if (i == 0) row_ptr[0] = 0;
}

// scatter edges sorted by dst, packed (dst<<16)|src; + mol_sorted scatter
__global__ void fill_ab(const int* __restrict__ src, const int* __restrict__ dst,
                        const int* __restrict__ row_ptr, int* __restrict__ cursor,
                        unsigned* __restrict__ ds_pack,
                        const int* __restrict__ mol_ids, const int* __restrict__ mrow,
                        int* __restrict__ mcur, int* __restrict__ mol_sorted) {
  int e = blockIdx.x * 256 + threadIdx.x;
  if (e < NE) {
    int d = dst[e];
    int pos = row_ptr[d] + atomicAdd(&cursor[d], 1);
    ds_pack[pos] = ((unsigned)d << 16) | (unsigned)src[e];
  }
  if (e < NA) {
    int m = mol_ids[e];
    int pos = mrow[m] + atomicAdd(&mcur[m], 1);
    mol_sorted[pos] = e;
  }
}

// ---- sub-run scan: opos[e] = index of e's sub-run (4-edge-window x dst) ----
__global__ void escan_p1(const unsigned* __restrict__ ds_pack, int* __restrict__ etmp,
                         int* __restrict__ eblk) {
  __shared__ int sh[1024];
  int t = threadIdx.x;
  int i = blockIdx.x * 1024 + t;
  int f = 0;
  if (i < NE)
    f = ((i & 3) == 0 || (ds_pack[i] >> 16) != (ds_pack[i - 1] >> 16)) ? 1 : 0;
  sh[t] = f;
  __syncthreads();
  for (int off = 1; off < 1024; off <<= 1) {
    int x = (t >= off) ? sh[t - off] : 0;
    __syncthreads();
    sh[t] += x;
    __syncthreads();
  }
  if (i < NE) etmp[i] = sh[t];
  if (t == 1023) eblk[blockIdx.x] = sh[1023];
}

// opos[i] = etmp[i] + prefix(eblk, bid) - 1; prefix via block tree-reduce
__global__ void escan_p3(const int* __restrict__ etmp, const int* __restrict__ eblk,
                         int* __restrict__ opos) {
  __shared__ int red[1024];
  int t = threadIdx.x;
  int bid = blockIdx.x;
  red[t] = (t < bid) ? eblk[t] : 0;  // bid <= 390 < 1024
  __syncthreads();
  for (int off = 512; off; off >>= 1) {
    if (t < off) red[t] += red[t + off];
    __syncthreads();
  }
  int spre = red[0];
  int i = bid * 1024 + t;
  if (i < NE) {
    int v = etmp[i] + spre - 1;
    opos[i] = v;
    if (i == NE - 1) opos[NE] = v + 1;
  }
}

// ---------------- node projection: PQb = bf16(s @ W')  (MFMA, LDS-free) ----
__global__ __launch_bounds__(256) void node_proj(const float* __restrict__ s_in,
                                                 const ushort_t* __restrict__ WpB,
                                                 ushort_t* __restrict__ PQb) {
  const int t = threadIdx.x;
  const int lane = t & 63, wv = t >> 6, quad = lane >> 4, l15 = lane & 15;
  const int n0 = blockIdx.x * 64 + wv * 16;
  int n = n0 + l15; if (n >= NA) n = NA - 1;
  union { short8 v; ushort_t u[8]; } a[4];
#pragma unroll
  for (int c = 0; c < 4; c++) {
    const float* p = s_in + (u64)n * 128 + c * 32 + quad * 8;
    float4 f0 = *(const float4*)(p);
    float4 f1 = *(const float4*)(p + 4);
    a[c].u[0] = f2bf(f0.x); a[c].u[1] = f2bf(f0.y);
    a[c].u[2] = f2bf(f0.z); a[c].u[3] = f2bf(f0.w);
    a[c].u[4] = f2bf(f1.x); a[c].u[5] = f2bf(f1.y);
    a[c].u[6] = f2bf(f1.z); a[c].u[7] = f2bf(f1.w);
  }
#pragma unroll
  for (int nt = 0; nt < 8; nt++) {
    f32x4 acc = {0.f, 0.f, 0.f, 0.f};
#pragma unroll
    for (int c = 0; c < 4; c++) {
      short8 b = *(const short8*)&WpB[((nt * 4 + c) * 64 + lane) * 8];
      acc = __builtin_amdgcn_mfma_f32_16x16x32_bf16(a[c].v, b, acc, 0, 0, 0);
    }
#pragma unroll
    for (int r = 0; r < 4; r++) {
      int nn = n0 + quad * 4 + r;
      if (nn < NA) PQb[(u64)nn * 128 + nt * 16 + l15] = f2bf(acc[r]);
    }
  }
}

// ------ fused edge MLP (MFMA) -> packed-bf16 SUB-RUN partial sums ----------
// 128 edges / workgroup; both tiles' P/Q gathers prefetched up front.
__global__ __launch_bounds__(256) void edge_msg(
    const ushort_t* __restrict__ PQb,
    const ushort_t* __restrict__ WhB, const ushort_t* __restrict__ WoB,
    const float* __restrict__ b_in, const float* __restrict__ b_h,
    const float* __restrict__ b_out,
    const unsigned* __restrict__ ds_pack, const int* __restrict__ opos,
    unsigned* __restrict__ m_buf) {
  __shared__ unsigned eps[128];
  __shared__ int ops[128];
  __shared__ ushort_t h2s[8][16 * 72];  // per-(wave,i) 16 x 64 bf16, pitch 72
  const int t = threadIdx.x;
  const int lane = t & 63, wv = t >> 6, quad = lane >> 4, l15 = lane & 15;
  const long long e0 = (long long)blockIdx.x * 128;  // NE % 128 == 0

  if (t < 128) {
    eps[t] = ds_pack[e0 + t];
    ops[t] = opos[e0 + t];
  }
  float bh[4], bo[8];
#pragma unroll
  for (int nt = 0; nt < 4; nt++) bh[nt] = b_h[nt * 16 + l15];
#pragma unroll
  for (int nt = 0; nt < 8; nt++) bo[nt] = b_out[nt * 16 + l15];
  float4 bi0[2], bi1[2];
#pragma unroll
  for (int c = 0; c < 2; c++) {
    bi0[c] = *(const float4*)(b_in + c * 32 + quad * 8);
    bi1[c] = *(const float4*)(b_in + c * 32 + quad * 8 + 4);
  }
  __syncthreads();

  // prefetch both tiles' gathers (8 outstanding 16B loads)
  union { ushort8 v; ushort_t u[8]; } pv[2][2], qv[2][2];
#pragma unroll
  for (int i = 0; i < 2; i++) {
    unsigned pk = eps[wv * 32 + i * 16 + l15];
    int da = pk >> 16, sa = pk & 0xffffu;
#pragma unroll
    for (int c = 0; c < 2; c++) {
      const int col = c * 32 + quad * 8;
      pv[i][c].v = *(const ushort8*)&PQb[(u64)da * 128 + col];
      qv[i][c].v = *(const ushort8*)&PQb[(u64)sa * 128 + 64 + col];
    }
  }

#pragma unroll
  for (int i = 0; i < 2; i++) {
    const int ebl = wv * 32 + i * 16;  // block-local tile base

    // A-frag of h1 = relu(P[dst] + Q[src] + b_in) from prefetched regs
    union { short8 v; ushort_t u[8]; } a1[2];
#pragma unroll
    for (int c = 0; c < 2; c++) {
      a1[c].u[0] = f2bf(fmaxf(bf2f(pv[i][c].u[0]) + bf2f(qv[i][c].u[0]) + bi0[c].x, 0.f));
      a1[c].u[1] = f2bf(fmaxf(bf2f(pv[i][c].u[1]) + bf2f(qv[i][c].u[1]) + bi0[c].y, 0.f));
      a1[c].u[2] = f2bf(fmaxf(bf2f(pv[i][c].u[2]) + bf2f(qv[i][c].u[2]) + bi0[c].z, 0.f));
      a1[c].u[3] = f2bf(fmaxf(bf2f(pv[i][c].u[3]) + bf2f(qv[i][c].u[3]) + bi0[c].w, 0.f));
      a1[c].u[4] = f2bf(fmaxf(bf2f(pv[i][c].u[4]) + bf2f(qv[i][c].u[4]) + bi1[c].x, 0.f));
      a1[c].u[5] = f2bf(fmaxf(bf2f(pv[i][c].u[5]) + bf2f(qv[i][c].u[5]) + bi1[c].y, 0.f));
      a1[c].u[6] = f2bf(fmaxf(bf2f(pv[i][c].u[6]) + bf2f(qv[i][c].u[6]) + bi1[c].z, 0.f));
      a1[c].u[7] = f2bf(fmaxf(bf2f(pv[i][c].u[7]) + bf2f(qv[i][c].u[7]) + bi1[c].w, 0.f));
    }

    // h2 = relu(h1 @ Wh + b_h)
    f32x4 acc1[4];
#pragma unroll
    for (int nt = 0; nt < 4; nt++) {
      f32x4 acc = {0.f, 0.f, 0.f, 0.f};
#pragma unroll
      for (int c = 0; c < 2; c++) {
        short8 b = *(const short8*)&WhB[((nt * 2 + c) * 64 + lane) * 8];
        acc = __builtin_amdgcn_mfma_f32_16x16x32_bf16(a1[c].v, b, acc, 0, 0, 0);
      }
      acc1[nt] = acc;
    }
    // D-layout -> row-major LDS (wave-private; same-wave RAW via lgkmcnt)
    ushort_t* hb = h2s[wv * 2 + i];
#pragma unroll
    for (int nt = 0; nt < 4; nt++)
#pragma unroll
      for (int r = 0; r < 4; r++)
        hb[(quad * 4 + r) * 72 + nt * 16 + l15] =
            f2bf(fmaxf(acc1[nt][r] + bh[nt], 0.f));

    union { short8 v; ushort_t u[8]; } a2[2];
#pragma unroll
    for (int c = 0; c < 2; c++)
      a2[c].v = *(const short8*)&hb[l15 * 72 + c * 32 + quad * 8];

    // m = relu(h2 @ Wout + b_out)
    f32x4 acc2[8];
#pragma unroll
    for (int nt = 0; nt < 8; nt++) {
      f32x4 acc = {0.f, 0.f, 0.f, 0.f};
#pragma unroll
      for (int c = 0; c < 2; c++) {
        short8 b = *(const short8*)&WoB[((nt * 2 + c) * 64 + lane) * 8];
        acc = __builtin_amdgcn_mfma_f32_16x16x32_bf16(a2[c].v, b, acc, 0, 0, 0);
      }
      acc2[nt] = acc;
    }

    // segmented sub-run flush: fp32 partials over the quad's 4 edges
    {
      const int base = ebl + quad * 4;
      int prev = (int)(eps[base] >> 16);
      int orow = ops[base];
      float run[8];
#pragma unroll
      for (int nt = 0; nt < 8; nt++) run[nt] = 0.f;
#pragma unroll
      for (int r = 0; r < 4; r++) {
        int er = base + r;
        int dcur = (int)(eps[er] >> 16);
        if (dcur != prev) {
          unsigned* rowp = m_buf + (u64)orow * 64;
#pragma unroll
          for (int k = 0; k < 4; k++)
            rowp[k * 16 + l15] =
                (unsigned)f2bf(run[2 * k]) | ((unsigned)f2bf(run[2 * k + 1]) << 16);
#pragma unroll
          for (int nt = 0; nt < 8; nt++) run[nt] = 0.f;
          prev = dcur; orow = ops[er];
        }
#pragma unroll
        for (int nt = 0; nt < 8; nt++)
          run[nt] += fmaxf(acc2[nt][r] + bo[nt], 0.f);
      }
      unsigned* rowp = m_buf + (u64)orow * 64;
#pragma unroll
      for (int k = 0; k < 4; k++)
        rowp[k * 16 + l15] =
            (unsigned)f2bf(run[2 * k]) | ((unsigned)f2bf(run[2 * k + 1]) << 16);
    }
  }
}

// ---- fused dst aggregation + projection over sub-run CSR ------------------
__global__ __launch_bounds__(256) void agg_proj(
    const unsigned* __restrict__ m_buf, const int* __restrict__ row_ptr,
    const int* __restrict__ opos,
    const ushort_t* __restrict__ WpB, ushort_t* __restrict__ PQb) {
  __shared__ ushort_t a_s[64 * 136];  // 64 rows x 128 bf16, pitch 136
  const int t = threadIdx.x;
  const int lane = t & 63, wv = t >> 6, quad = lane >> 4, l15 = lane & 15;
  const int n0 = blockIdx.x * 64;

  for (int r = 0; r < 16; r++) {
    const int d = n0 + wv * 16 + r;
    float s0 = 0.f, s1 = 0.f;
    if (d < NA) {
      int ob = opos[row_ptr[d]], oe = opos[row_ptr[d + 1]];
      int n = oe - ob;
      float t0 = 0.f, t1 = 0.f, u0 = 0.f, u1 = 0.f, v0 = 0.f, v1 = 0.f;
      int full = n & ~3;
      int e = ob;
      for (; e < ob + full; e += 4) {
        unsigned w0 = m_buf[(u64)(e + 0) * 64 + lane];
        unsigned w1 = m_buf[(u64)(e + 1) * 64 + lane];
        unsigned w2 = m_buf[(u64)(e + 2) * 64 + lane];
        unsigned w3 = m_buf[(u64)(e + 3) * 64 + lane];
        s0 += bf2f(w0 & 0xffffu); s1 += bf2f(w0 >> 16);
        t0 += bf2f(w1 & 0xffffu); t1 += bf2f(w1 >> 16);
        u0 += bf2f(w2 & 0xffffu); u1 += bf2f(w2 >> 16);
        v0 += bf2f(w3 & 0xffffu); v1 += bf2f(w3 >> 16);
      }
      int rem = n - full;
      if (rem > 0) {
        int i1 = (rem > 1) ? e + 1 : e;
        int i2 = (rem > 2) ? e + 2 : e;
        unsigned w0 = m_buf[(u64)e * 64 + lane];
        unsigned w1 = m_buf[(u64)i1 * 64 + lane];
        unsigned w2 = m_buf[(u64)i2 * 64 + lane];
        s0 += bf2f(w0 & 0xffffu); s1 += bf2f(w0 >> 16);
        if (rem > 1) { t0 += bf2f(w1 & 0xffffu); t1 += bf2f(w1 >> 16); }
        if (rem > 2) { u0 += bf2f(w2 & 0xffffu); u1 += bf2f(w2 >> 16); }
      }
      s0 = (s0 + t0) + (u0 + v0);
      s1 = (s1 + t1) + (u1 + v1);
    }
    const int row = wv * 16 + r;
    a_s[row * 136 + quad * 32 + l15] = f2bf(s0);
    a_s[row * 136 + quad * 32 + 16 + l15] = f2bf(s1);
  }
  // wave-private tile: same-wave LDS RAW ordered by lgkmcnt, no barrier

  short8 a[4];
#pragma unroll
  for (int c = 0; c < 4; c++)
    a[c] = *(const short8*)&a_s[(wv * 16 + l15) * 136 + c * 32 + quad * 8];
#pragma unroll
  for (int nt = 0; nt < 8; nt++) {
    f32x4 acc = {0.f, 0.f, 0.f, 0.f};
#pragma unroll
    for (int c = 0; c < 4; c++) {
      short8 b = *(const short8*)&WpB[((nt * 4 + c) * 64 + lane) * 8];
      acc = __builtin_amdgcn_mfma_f32_16x16x32_bf16(a[c], b, acc, 0, 0, 0);
    }
#pragma unroll
    for (int r = 0; r < 4; r++) {
      int nn = n0 + wv * 16 + quad * 4 + r;
      if (nn < NA) PQb[(u64)nn * 128 + nt * 16 + l15] = f2bf(acc[r]);
    }
  }
}

// -------- final-step dst aggregation over sub-run CSR, no atomics ----------
__global__ __launch_bounds__(256) void agg_dst(const unsigned* __restrict__ m_buf,
                                               const int* __restrict__ row_ptr,
                                               const int* __restrict__ opos,
                                               float* __restrict__ s_next) {
  int w = (blockIdx.x * 256 + threadIdx.x) >> 6;  // dst id
  int lane = threadIdx.x & 63;
  if (w >= NA) return;
  int ob = opos[row_ptr[w]], oe = opos[row_ptr[w + 1]];
  int n = oe - ob;
  float s0 = 0.f, s1 = 0.f, t0 = 0.f, t1 = 0.f, u0 = 0.f, u1 = 0.f, v0 = 0.f, v1 = 0.f;
  int full = n & ~3;
  int e = ob;
  for (; e < ob + full; e += 4) {
    unsigned w0 = m_buf[(u64)(e + 0) * 64 + lane];
    unsigned w1 = m_buf[(u64)(e + 1) * 64 + lane];
    unsigned w2 = m_buf[(u64)(e + 2) * 64 + lane];
    unsigned w3 = m_buf[(u64)(e + 3) * 64 + lane];
    s0 += bf2f(w0 & 0xffffu); s1 += bf2f(w0 >> 16);
    t0 += bf2f(w1 & 0xffffu); t1 += bf2f(w1 >> 16);
    u0 += bf2f(w2 & 0xffffu); u1 += bf2f(w2 >> 16);
    v0 += bf2f(w3 & 0xffffu); v1 += bf2f(w3 >> 16);
  }
  int rem = n - full;
  if (rem > 0) {
    int i1 = (rem > 1) ? e + 1 : e;
    int i2 = (rem > 2) ? e + 2 : e;
    unsigned w0 = m_buf[(u64)e * 64 + lane];
    unsigned w1 = m_buf[(u64)i1 * 64 + lane];
    unsigned w2 = m_buf[(u64)i2 * 64 + lane];
    s0 += bf2f(w0 & 0xffffu); s1 += bf2f(w0 >> 16);
    if (rem > 1) { t0 += bf2f(w1 & 0xffffu); t1 += bf2f(w1 >> 16); }
    if (rem > 2) { u0 += bf2f(w2 & 0xffffu); u1 += bf2f(w2 >> 16); }
  }
  s0 = (s0 + t0) + (u0 + v0);
  s1 = (s1 + t1) + (u1 + v1);
  int k = lane >> 4, l15 = lane & 15;
  s_next[(u64)w * 128 + k * 32 + l15] = s0;
  s_next[(u64)w * 128 + k * 32 + 16 + l15] = s1;
}

// ------- molecule aggregation: chunked segmented sum over mol_sorted -------
__global__ __launch_bounds__(128) void agg_mol(const float* __restrict__ s_fin,
                                               const int* __restrict__ mol_sorted,
                                               const int* __restrict__ mol_ids,
                                               float* __restrict__ mol_repr) {
  __shared__ int rows[128], mids[128];
  const int c = threadIdx.x;
  const int base = blockIdx.x * 128;
  int n = NA - base; if (n > 128) n = 128;
  if (c < n) {
    int r = mol_sorted[base + c];
    rows[c] = r;
    mids[c] = mol_ids[r];
  }
  __syncthreads();
  float run = 0.f;
  int prev = mids[0];
#pragma unroll 4
  for (int i = 0; i < n; i++) {
    int m = mids[i];
    if (m != prev) {
      atomicAdd(&mol_repr[(u64)prev * 128 + c], run);
      run = 0.f; prev = m;
    }
    run += s_fin[(u64)rows[i] * 128 + c];
  }
  atomicAdd(&mol_repr[(u64)prev * 128 + c], run);
}

// ---------------- final tiny MLP per molecule ----------------
__global__ void final_mlp(const float* __restrict__ mol_repr,
                          const float* __restrict__ fc1_w, const float* __restrict__ fc1_b,
                          const float* __restrict__ fc2_w, const float* __restrict__ fc2_b,
                          const float* __restrict__ out_w, const float* __restrict__ out_b,
                          float* __restrict__ out) {
  int m = blockIdx.x, j = threadIdx.x;
  __shared__ float h1sh[64], h2sh[64];
  const float* mr = mol_repr + (u64)m * DF;
  float acc = fc1_b[j];
  for (int d = 0; d < DF; d++) acc = fmaf(mr[d], fc1_w[d * 64 + j], acc);
  h1sh[j] = fmaxf(acc, 0.f);
  __syncthreads();
  acc = fc2_b[j];
  for (int k = 0; k < 64; k++) acc = fmaf(h1sh[k], fc2_w[k * 64 + j], acc);
  h2sh[j] = fmaxf(acc, 0.f);
  __syncthreads();
  if (j < NOUT) {
    acc = out_b[j];
    for (int k = 0; k < 64; k++) acc = fmaf(h2sh[k], out_w[k * NOUT + j], acc);
    out[(u64)m * NOUT + j] = acc;
  }
}

extern "C" void kernel_launch(void* const* d_in, const int* in_sizes, int n_in,
                              void* d_out, int out_size, void* d_ws, size_t ws_size,
                              hipStream_t stream) {
  const float* states = (const float*)d_in[0];
  const float* Win    = (const float*)d_in[1];
  const float* b_in   = (const float*)d_in[2];
  const float* Wh     = (const float*)d_in[3];
  const float* b_h    = (const float*)d_in[4];
  const float* Wout   = (const float*)d_in[5];
  const float* b_out  = (const float*)d_in[6];
  const float* fc1_w  = (const float*)d_in[7];
  const float* fc1_b  = (const float*)d_in[8];
  const float* fc2_w  = (const float*)d_in[9];
  const float* fc2_b  = (const float*)d_in[10];
  const float* out_w  = (const float*)d_in[11];
  const float* out_b  = (const float*)d_in[12];
  const int* src      = (const int*)d_in[13];
  const int* dst      = (const int*)d_in[14];
  const int* mol_ids  = (const int*)d_in[15];

  char* ws = (char*)d_ws;
  u64 o = 0;
  auto alloc = [&](u64 bytes) {
    void* p = ws + o;
    o += (bytes + 255) & ~255ull;
    return p;
  };
  unsigned* m_buf = (unsigned*)alloc((u64)NE * 64 * 4);   // worst-case R = NE
  ushort_t* PQb  = (ushort_t*)alloc((u64)NA * DF * 2);
  float* sA      = (float*)alloc((u64)NA * DF * 4);
  ushort_t* WpB  = (ushort_t*)alloc(3 * 16384 * 2);
  ushort_t* WhB  = (ushort_t*)alloc(3 * 4096 * 2);
  ushort_t* WoB  = (ushort_t*)alloc(3 * 8192 * 2);
  // zero-init block (single memset)
  char* zbase    = ws + o;
  float* molr    = (float*)alloc((u64)NMOL * DF * 4);
  int* counts    = (int*)alloc((u64)NA * 4);
  int* cursor    = (int*)alloc((u64)NA * 4);
  int* mcnt      = (int*)alloc(NMOL * 4);
  int* mcur      = (int*)alloc(NMOL * 4);
  u64 zbytes     = (u64)((ws + o) - zbase);
  int* row_ptr   = (int*)alloc((u64)(NA + 1) * 4);
  int* mrow      = (int*)alloc((NMOL + 1) * 4);
  unsigned* ds_pack = (unsigned*)alloc((u64)NE * 4);
  int* mol_sorted = (int*)alloc((u64)NA * 4);
  int* scan_tmp  = (int*)alloc((u64)NA * 4);
  int* blk_sums  = (int*)alloc(64 * 4);
  int* opos      = (int*)alloc((u64)(NE + 1) * 4);
  int* etmp      = (int*)alloc((u64)NE * 4);
  int* eblk      = (int*)alloc(512 * 4);
  (void)ws_size; (void)in_sizes; (void)n_in; (void)out_size;

  const int NSCAN = (NA + 1023) / 1024;   // 49
  const int NESCAN = (NE + 1023) / 1024;  // 391

  hipMemsetAsync(zbase, 0, zbytes, stream);

  setup_a<<<(NE + 255) / 256, 256, 0, stream>>>(Win, Wh, Wout, WpB, WhB, WoB,
                                                dst, mol_ids, counts, mcnt);
  scan_phase1<<<NSCAN, 1024, 0, stream>>>(counts, scan_tmp, blk_sums, mcnt, mrow);
  scan_phase3<<<NSCAN, 1024, 0, stream>>>(scan_tmp, blk_sums, row_ptr);
  fill_ab<<<(NE + 255) / 256, 256, 0, stream>>>(src, dst, row_ptr, cursor, ds_pack,
                                                mol_ids, mrow, mcur, mol_sorted);
  escan_p1<<<NESCAN, 1024, 0, stream>>>(ds_pack, etmp, eblk);
  escan_p3<<<NESCAN, 1024, 0, stream>>>(etmp, eblk, opos);

  node_proj<<<(NA + 63) / 64, 256, 0, stream>>>(states, WpB, PQb);
  for (int t = 0; t < NSTEP; t++) {
    edge_msg<<<(NE + 127) / 128, 256, 0, stream>>>(
        PQb, WhB + t * 4096, WoB + t * 8192,
        b_in + t * 64, b_h + t * 64, b_out + t * 128, ds_pack, opos, m_buf);
    if (t < NSTEP - 1) {
      agg_proj<<<(NA + 63) / 64, 256, 0, stream>>>(m_buf, row_ptr, opos,
                                                   WpB + (t + 1) * 16384, PQb);
    } else {
      agg_dst<<<(NA * 64 + 255) / 256, 256, 0, stream>>>(m_buf, row_ptr, opos, sA);
    }
  }
  agg_mol<<<(NA + 127) / 128, 128, 0, stream>>>(sA, mol_sorted, mol_ids, molr);
  final_mlp<<<NMOL, 64, 0, stream>>>(molr, fc1_w, fc1_b, fc2_w, fc2_b, out_w, out_b,
                                     (float*)d_out);
}

// Round 11
// 389.301 us; speedup vs baseline: 1.6953x; 1.1082x over previous
//
#include <hip/hip_runtime.h>

typedef unsigned long long u64;
typedef unsigned short ushort_t;

#define NA 50000
#define NE 400000
#define DF 128
#define HID 64
#define NMOL 256
#define NOUT 32
#define NSTEP 3

typedef __attribute__((ext_vector_type(8))) short short8;
typedef __attribute__((ext_vector_type(8))) unsigned short ushort8;
typedef __attribute__((ext_vector_type(4))) float f32x4;

static __device__ __forceinline__ ushort_t f2bf(float f) {
  union { float f; unsigned u; } v; v.f = f;
  unsigned r = v.u + 0x7fffu + ((v.u >> 16) & 1u);
  return (ushort_t)(r >> 16);
}
static __device__ __forceinline__ float bf2f(unsigned b) {
  union { unsigned u; float f; } v; v.u = b << 16;
  return v.f;
}

// -------- fused setup: pack weights (B-frag order) + degree histograms -----
__global__ void setup_a(const float* __restrict__ Win, const float* __restrict__ Wh,
                        const float* __restrict__ Wout,
                        ushort_t* __restrict__ WpB, ushort_t* __restrict__ WhB,
                        ushort_t* __restrict__ WoB,
                        const int* __restrict__ dst, const int* __restrict__ mol_ids,
                        int* __restrict__ counts, int* __restrict__ mcnt) {
  int g = blockIdx.x * 256 + threadIdx.x;
  if (g < 3 * 16384) {
    int tt = g / 16384, r = g % 16384;
    int j = r & 7, lane = (r >> 3) & 63, f = r >> 9;
    int kc = f & 3, nt = f >> 2;
    int k = kc * 32 + (lane >> 4) * 8 + j;
    int n = nt * 16 + (lane & 15);
    float v = (n < 64) ? Win[tt * 16384 + k * 64 + n]
                       : Win[tt * 16384 + (128 + k) * 64 + (n - 64)];
    WpB[g] = f2bf(v);
  }
  int g2 = g - 3 * 16384;
  if (g2 >= 0 && g2 < 3 * 4096) {
    int tt = g2 / 4096, r = g2 % 4096;
    int j = r & 7, lane = (r >> 3) & 63, f = r >> 9;
    int kc = f & 1, nt = f >> 1;
    int k = kc * 32 + (lane >> 4) * 8 + j;
    int n = nt * 16 + (lane & 15);
    WhB[g2] = f2bf(Wh[tt * 4096 + k * 64 + n]);
  }
  int g3 = g2 - 3 * 4096;
  if (g3 >= 0 && g3 < 3 * 8192) {
    int tt = g3 / 8192, r = g3 % 8192;
    int j = r & 7, lane = (r >> 3) & 63, f = r >> 9;
    int kc = f & 1, nt = f >> 1;
    int k = kc * 32 + (lane >> 4) * 8 + j;
    int n = nt * 16 + (lane & 15);
    WoB[g3] = f2bf(Wout[tt * 8192 + k * 128 + n]);
  }
  if (g < NE) atomicAdd(&counts[dst[g]], 1);
  if (g < NA) atomicAdd(&mcnt[mol_ids[g]], 1);
}

// per-1024-block inclusive scan of counts; last block also scans mol histogram
__global__ void scan_phase1(const int* __restrict__ counts, int* __restrict__ tmp,
                            int* __restrict__ blk,
                            const int* __restrict__ mcnt, int* __restrict__ mrow) {
  __shared__ int sh[1024];
  int t = threadIdx.x;
  int i = blockIdx.x * 1024 + t;
  sh[t] = (i < NA) ? counts[i] : 0;
  __syncthreads();
  for (int off = 1; off < 1024; off <<= 1) {
    int x = (t >= off) ? sh[t - off] : 0;
    __syncthreads();
    sh[t] += x;
    __syncthreads();
  }
  if (i < NA) tmp[i] = sh[t];
  if (t == 1023) blk[blockIdx.x] = sh[1023];
  if (blockIdx.x == gridDim.x - 1) {  // fold in the molecule scan
    __syncthreads();
    sh[t] = (t < NMOL) ? mcnt[t] : 0;
    __syncthreads();
    for (int off = 1; off < NMOL; off <<= 1) {
      int x = (t >= off && t < NMOL) ? sh[t - off] : 0;
      __syncthreads();
      if (t < NMOL) sh[t] += x;
      __syncthreads();
    }
    if (t < NMOL) mrow[t + 1] = sh[t];
    if (t == 0) mrow[0] = 0;
  }
}

// row_ptr[i+1] = tmp[i] + prefix(blk, bid); prefix computed by wave-reduce
__global__ void scan_phase3(const int* __restrict__ tmp, const int* __restrict__ blk,
                            int* __restrict__ row_ptr) {
  __shared__ int spre_sh;
  int t = threadIdx.x;
  int bid = blockIdx.x;
  if (t < 64) {
    int v = (t < bid) ? blk[t] : 0;  // bid <= 48 < 64
    for (int off = 32; off; off >>= 1) v += __shfl_down(v, off);
    if (t == 0) spre_sh = v;
  }
  __syncthreads();
  int spre = spre_sh;
  int i = bid * 1024 + t;
  if (i < NA) row_ptr[i + 1] = tmp[i] + spre;
  if (i == 0) row_ptr[0] = 0;
}

// scatter edges sorted by dst, packed (dst<<16)|src; + mol_sorted scatter
__global__ void fill_ab(const int* __restrict__ src, const int* __restrict__ dst,
                        const int* __restrict__ row_ptr, int* __restrict__ cursor,
                        unsigned* __restrict__ ds_pack,
                        const int* __restrict__ mol_ids, const int* __restrict__ mrow,
                        int* __restrict__ mcur, int* __restrict__ mol_sorted) {
  int e = blockIdx.x * 256 + threadIdx.x;
  if (e < NE) {
    int d = dst[e];
    int pos = row_ptr[d] + atomicAdd(&cursor[d], 1);
    ds_pack[pos] = ((unsigned)d << 16) | (unsigned)src[e];
  }
  if (e < NA) {
    int m = mol_ids[e];
    int pos = mrow[m] + atomicAdd(&mcur[m], 1);
    mol_sorted[pos] = e;
  }
}

// ---- sub-run scan: opos[e] = index of e's sub-run (4-edge-window x dst) ----
__global__ void escan_p1(const unsigned* __restrict__ ds_pack, int* __restrict__ etmp,
                         int* __restrict__ eblk) {
  __shared__ int sh[1024];
  int t = threadIdx.x;
  int i = blockIdx.x * 1024 + t;
  int f = 0;
  if (i < NE)
    f = ((i & 3) == 0 || (ds_pack[i] >> 16) != (ds_pack[i - 1] >> 16)) ? 1 : 0;
  sh[t] = f;
  __syncthreads();
  for (int off = 1; off < 1024; off <<= 1) {
    int x = (t >= off) ? sh[t - off] : 0;
    __syncthreads();
    sh[t] += x;
    __syncthreads();
  }
  if (i < NE) etmp[i] = sh[t];
  if (t == 1023) eblk[blockIdx.x] = sh[1023];
}

// opos[i] = etmp[i] + prefix(eblk, bid) - 1; prefix via block tree-reduce
__global__ void escan_p3(const int* __restrict__ etmp, const int* __restrict__ eblk,
                         int* __restrict__ opos) {
  __shared__ int red[1024];
  int t = threadIdx.x;
  int bid = blockIdx.x;
  red[t] = (t < bid) ? eblk[t] : 0;  // bid <= 390 < 1024
  __syncthreads();
  for (int off = 512; off; off >>= 1) {
    if (t < off) red[t] += red[t + off];
    __syncthreads();
  }
  int spre = red[0];
  int i = bid * 1024 + t;
  if (i < NE) {
    int v = etmp[i] + spre - 1;
    opos[i] = v;
    if (i == NE - 1) opos[NE] = v + 1;
  }
}

// orow[d] = opos[row_ptr[d]] : sub-run CSR directly indexed by dst
__global__ void make_orow(const int* __restrict__ row_ptr, const int* __restrict__ opos,
                          int* __restrict__ orow) {
  int i = blockIdx.x * 256 + threadIdx.x;
  if (i <= NA) orow[i] = opos[row_ptr[i]];
}

// -------- node projection: PQb = bf16(s @ W' [+ b_in on P-cols]) -----------
__global__ __launch_bounds__(256) void node_proj(const float* __restrict__ s_in,
                                                 const ushort_t* __restrict__ WpB,
                                                 const float* __restrict__ b_in,
                                                 ushort_t* __restrict__ PQb) {
  const int t = threadIdx.x;
  const int lane = t & 63, wv = t >> 6, quad = lane >> 4, l15 = lane & 15;
  const int n0 = blockIdx.x * 64 + wv * 16;
  int n = n0 + l15; if (n >= NA) n = NA - 1;
  union { short8 v; ushort_t u[8]; } a[4];
#pragma unroll
  for (int c = 0; c < 4; c++) {
    const float* p = s_in + (u64)n * 128 + c * 32 + quad * 8;
    float4 f0 = *(const float4*)(p);
    float4 f1 = *(const float4*)(p + 4);
    a[c].u[0] = f2bf(f0.x); a[c].u[1] = f2bf(f0.y);
    a[c].u[2] = f2bf(f0.z); a[c].u[3] = f2bf(f0.w);
    a[c].u[4] = f2bf(f1.x); a[c].u[5] = f2bf(f1.y);
    a[c].u[6] = f2bf(f1.z); a[c].u[7] = f2bf(f1.w);
  }
  float binv[4];
#pragma unroll
  for (int nt = 0; nt < 4; nt++) binv[nt] = b_in[nt * 16 + l15];
#pragma unroll
  for (int nt = 0; nt < 8; nt++) {
    f32x4 acc = {0.f, 0.f, 0.f, 0.f};
#pragma unroll
    for (int c = 0; c < 4; c++) {
      short8 b = *(const short8*)&WpB[((nt * 4 + c) * 64 + lane) * 8];
      acc = __builtin_amdgcn_mfma_f32_16x16x32_bf16(a[c].v, b, acc, 0, 0, 0);
    }
    float bias = (nt < 4) ? binv[nt] : 0.f;
#pragma unroll
    for (int r = 0; r < 4; r++) {
      int nn = n0 + quad * 4 + r;
      if (nn < NA) PQb[(u64)nn * 128 + nt * 16 + l15] = f2bf(acc[r] + bias);
    }
  }
}

// ------ fused edge MLP (MFMA) -> packed-bf16 SUB-RUN partial sums ----------
// 128 edges / workgroup; both tiles' P/Q gathers prefetched up front.
// b_in pre-folded into P columns of PQb.
__global__ __launch_bounds__(256) void edge_msg(
    const ushort_t* __restrict__ PQb,
    const ushort_t* __restrict__ WhB, const ushort_t* __restrict__ WoB,
    const float* __restrict__ b_h, const float* __restrict__ b_out,
    const unsigned* __restrict__ ds_pack, const int* __restrict__ opos,
    unsigned* __restrict__ m_buf) {
  __shared__ unsigned eps[128];
  __shared__ int ops[128];
  __shared__ ushort_t h2s[4][16 * 72];  // per-wave 16 x 64 bf16 (reused across i)
  const int t = threadIdx.x;
  const int lane = t & 63, wv = t >> 6, quad = lane >> 4, l15 = lane & 15;
  const long long e0 = (long long)blockIdx.x * 128;  // NE % 128 == 0

  if (t < 128) {
    eps[t] = ds_pack[e0 + t];
    ops[t] = opos[e0 + t];
  }
  float bh[4], bo[8];
#pragma unroll
  for (int nt = 0; nt < 4; nt++) bh[nt] = b_h[nt * 16 + l15];
#pragma unroll
  for (int nt = 0; nt < 8; nt++) bo[nt] = b_out[nt * 16 + l15];
  __syncthreads();

  // prefetch both tiles' gathers (8 outstanding 16B loads)
  union { ushort8 v; ushort_t u[8]; } pv[2][2], qv[2][2];
#pragma unroll
  for (int i = 0; i < 2; i++) {
    unsigned pk = eps[wv * 32 + i * 16 + l15];
    int da = pk >> 16, sa = pk & 0xffffu;
#pragma unroll
    for (int c = 0; c < 2; c++) {
      const int col = c * 32 + quad * 8;
      pv[i][c].v = *(const ushort8*)&PQb[(u64)da * 128 + col];
      qv[i][c].v = *(const ushort8*)&PQb[(u64)sa * 128 + 64 + col];
    }
  }

#pragma unroll
  for (int i = 0; i < 2; i++) {
    const int ebl = wv * 32 + i * 16;  // block-local tile base

    // A-frag of h1 = relu(P'[dst] + Q[src]) from prefetched regs
    union { short8 v; ushort_t u[8]; } a1[2];
#pragma unroll
    for (int c = 0; c < 2; c++) {
#pragma unroll
      for (int k = 0; k < 8; k++)
        a1[c].u[k] = f2bf(fmaxf(bf2f(pv[i][c].u[k]) + bf2f(qv[i][c].u[k]), 0.f));
    }

    // h2 = relu(h1 @ Wh + b_h)
    f32x4 acc1[4];
#pragma unroll
    for (int nt = 0; nt < 4; nt++) {
      f32x4 acc = {0.f, 0.f, 0.f, 0.f};
#pragma unroll
      for (int c = 0; c < 2; c++) {
        short8 b = *(const short8*)&WhB[((nt * 2 + c) * 64 + lane) * 8];
        acc = __builtin_amdgcn_mfma_f32_16x16x32_bf16(a1[c].v, b, acc, 0, 0, 0);
      }
      acc1[nt] = acc;
    }
    // D-layout -> row-major LDS (wave-private; same-wave RAW/WAR via lgkmcnt)
    ushort_t* hb = h2s[wv];
#pragma unroll
    for (int nt = 0; nt < 4; nt++)
#pragma unroll
      for (int r = 0; r < 4; r++)
        hb[(quad * 4 + r) * 72 + nt * 16 + l15] =
            f2bf(fmaxf(acc1[nt][r] + bh[nt], 0.f));

    union { short8 v; ushort_t u[8]; } a2[2];
#pragma unroll
    for (int c = 0; c < 2; c++)
      a2[c].v = *(const short8*)&hb[l15 * 72 + c * 32 + quad * 8];

    // m = relu(h2 @ Wout + b_out)
    f32x4 acc2[8];
#pragma unroll
    for (int nt = 0; nt < 8; nt++) {
      f32x4 acc = {0.f, 0.f, 0.f, 0.f};
#pragma unroll
      for (int c = 0; c < 2; c++) {
        short8 b = *(const short8*)&WoB[((nt * 2 + c) * 64 + lane) * 8];
        acc = __builtin_amdgcn_mfma_f32_16x16x32_bf16(a2[c].v, b, acc, 0, 0, 0);
      }
      acc2[nt] = acc;
    }

    // segmented sub-run flush: fp32 partials over the quad's 4 edges
    {
      const int base = ebl + quad * 4;
      int prev = (int)(eps[base] >> 16);
      int orow_ = ops[base];
      float run[8];
#pragma unroll
      for (int nt = 0; nt < 8; nt++) run[nt] = 0.f;
#pragma unroll
      for (int r = 0; r < 4; r++) {
        int er = base + r;
        int dcur = (int)(eps[er] >> 16);
        if (dcur != prev) {
          unsigned* rowp = m_buf + (u64)orow_ * 64;
#pragma unroll
          for (int k = 0; k < 4; k++)
            rowp[k * 16 + l15] =
                (unsigned)f2bf(run[2 * k]) | ((unsigned)f2bf(run[2 * k + 1]) << 16);
#pragma unroll
          for (int nt = 0; nt < 8; nt++) run[nt] = 0.f;
          prev = dcur; orow_ = ops[er];
        }
#pragma unroll
        for (int nt = 0; nt < 8; nt++)
          run[nt] += fmaxf(acc2[nt][r] + bo[nt], 0.f);
      }
      unsigned* rowp = m_buf + (u64)orow_ * 64;
#pragma unroll
      for (int k = 0; k < 4; k++)
        rowp[k * 16 + l15] =
            (unsigned)f2bf(run[2 * k]) | ((unsigned)f2bf(run[2 * k + 1]) << 16);
    }
  }
}

// ---- fused dst aggregation + projection over sub-run CSR (orow) -----------
__global__ __launch_bounds__(256) void agg_proj(
    const unsigned* __restrict__ m_buf, const int* __restrict__ orow,
    const ushort_t* __restrict__ WpB, const float* __restrict__ b_in,
    ushort_t* __restrict__ PQb) {
  __shared__ ushort_t a_s[64 * 136];  // 64 rows x 128 bf16, pitch 136
  const int t = threadIdx.x;
  const int lane = t & 63, wv = t >> 6, quad = lane >> 4, l15 = lane & 15;
  const int n0 = blockIdx.x * 64;

  for (int r = 0; r < 16; r++) {
    const int d = n0 + wv * 16 + r;
    float s0 = 0.f, s1 = 0.f;
    if (d < NA) {
      int ob = orow[d], oe = orow[d + 1];
      int n = oe - ob;
      float t0 = 0.f, t1 = 0.f, u0 = 0.f, u1 = 0.f, v0 = 0.f, v1 = 0.f;
      int full = n & ~3;
      int e = ob;
      for (; e < ob + full; e += 4) {
        unsigned w0 = m_buf[(u64)(e + 0) * 64 + lane];
        unsigned w1 = m_buf[(u64)(e + 1) * 64 + lane];
        unsigned w2 = m_buf[(u64)(e + 2) * 64 + lane];
        unsigned w3 = m_buf[(u64)(e + 3) * 64 + lane];
        s0 += bf2f(w0 & 0xffffu); s1 += bf2f(w0 >> 16);
        t0 += bf2f(w1 & 0xffffu); t1 += bf2f(w1 >> 16);
        u0 += bf2f(w2 & 0xffffu); u1 += bf2f(w2 >> 16);
        v0 += bf2f(w3 & 0xffffu); v1 += bf2f(w3 >> 16);
      }
      int rem = n - full;
      if (rem > 0) {
        int i1 = (rem > 1) ? e + 1 : e;
        int i2 = (rem > 2) ? e + 2 : e;
        unsigned w0 = m_buf[(u64)e * 64 + lane];
        unsigned w1 = m_buf[(u64)i1 * 64 + lane];
        unsigned w2 = m_buf[(u64)i2 * 64 + lane];
        s0 += bf2f(w0 & 0xffffu); s1 += bf2f(w0 >> 16);
        if (rem > 1) { t0 += bf2f(w1 & 0xffffu); t1 += bf2f(w1 >> 16); }
        if (rem > 2) { u0 += bf2f(w2 & 0xffffu); u1 += bf2f(w2 >> 16); }
      }
      s0 = (s0 + t0) + (u0 + v0);
      s1 = (s1 + t1) + (u1 + v1);
    }
    const int row = wv * 16 + r;
    a_s[row * 136 + quad * 32 + l15] = f2bf(s0);
    a_s[row * 136 + quad * 32 + 16 + l15] = f2bf(s1);
  }
  // wave-private tile: same-wave LDS RAW ordered by lgkmcnt, no barrier

  float binv[4];
#pragma unroll
  for (int nt = 0; nt < 4; nt++) binv[nt] = b_in[nt * 16 + l15];
  short8 a[4];
#pragma unroll
  for (int c = 0; c < 4; c++)
    a[c] = *(const short8*)&a_s[(wv * 16 + l15) * 136 + c * 32 + quad * 8];
#pragma unroll
  for (int nt = 0; nt < 8; nt++) {
    f32x4 acc = {0.f, 0.f, 0.f, 0.f};
#pragma unroll
    for (int c = 0; c < 4; c++) {
      short8 b = *(const short8*)&WpB[((nt * 4 + c) * 64 + lane) * 8];
      acc = __builtin_amdgcn_mfma_f32_16x16x32_bf16(a[c], b, acc, 0, 0, 0);
    }
    float bias = (nt < 4) ? binv[nt] : 0.f;
#pragma unroll
    for (int r = 0; r < 4; r++) {
      int nn = n0 + wv * 16 + quad * 4 + r;
      if (nn < NA) PQb[(u64)nn * 128 + nt * 16 + l15] = f2bf(acc[r] + bias);
    }
  }
}

// ---- final aggregation: m_buf sub-runs -> per-mol sums directly -----------
// block = 64 mol-sorted atoms, wave = 16 contiguous; lane = col-dword.
__global__ __launch_bounds__(256) void agg_mol2(
    const unsigned* __restrict__ m_buf, const int* __restrict__ orow,
    const int* __restrict__ mol_sorted, const int* __restrict__ mol_ids,
    float* __restrict__ mol_repr) {
  __shared__ int rows[64], mids[64];
  const int t = threadIdx.x;
  const int lane = t & 63, wv = t >> 6;
  const int base = blockIdx.x * 64;
  if (t < 64) {
    int idx = base + t;
    int r = (idx < NA) ? mol_sorted[idx] : 0;
    rows[t] = r;
    mids[t] = (idx < NA) ? mol_ids[r] : -1;
  }
  __syncthreads();
  const int c0 = (lane >> 4) * 32 + (lane & 15);  // unpacked cols c0, c0+16
  float r0 = 0.f, r1 = 0.f;
  int prev = mids[wv * 16];
  for (int i = 0; i < 16; i++) {
    int li = wv * 16 + i;
    int m = mids[li];
    if (m != prev) {
      if (prev >= 0) {
        atomicAdd(&mol_repr[(u64)prev * 128 + c0], r0);
        atomicAdd(&mol_repr[(u64)prev * 128 + c0 + 16], r1);
      }
      r0 = 0.f; r1 = 0.f; prev = m;
    }
    if (m >= 0) {
      int d = rows[li];
      int ob = orow[d], oe = orow[d + 1];
      int n = oe - ob;
      float t0 = 0.f, t1 = 0.f, u0 = 0.f, u1 = 0.f, v0 = 0.f, v1 = 0.f;
      int full = n & ~3;
      int e = ob;
      for (; e < ob + full; e += 4) {
        unsigned w0 = m_buf[(u64)(e + 0) * 64 + lane];
        unsigned w1 = m_buf[(u64)(e + 1) * 64 + lane];
        unsigned w2 = m_buf[(u64)(e + 2) * 64 + lane];
        unsigned w3 = m_buf[(u64)(e + 3) * 64 + lane];
        r0 += bf2f(w0 & 0xffffu); r1 += bf2f(w0 >> 16);
        t0 += bf2f(w1 & 0xffffu); t1 += bf2f(w1 >> 16);
        u0 += bf2f(w2 & 0xffffu); u1 += bf2f(w2 >> 16);
        v0 += bf2f(w3 & 0xffffu); v1 += bf2f(w3 >> 16);
      }
      int rem = n - full;
      if (rem > 0) {
        int i1 = (rem > 1) ? e + 1 : e;
        int i2 = (rem > 2) ? e + 2 : e;
        unsigned w0 = m_buf[(u64)e * 64 + lane];
        unsigned w1 = m_buf[(u64)i1 * 64 + lane];
        unsigned w2 = m_buf[(u64)i2 * 64 + lane];
        r0 += bf2f(w0 & 0xffffu); r1 += bf2f(w0 >> 16);
        if (rem > 1) { t0 += bf2f(w1 & 0xffffu); t1 += bf2f(w1 >> 16); }
        if (rem > 2) { u0 += bf2f(w2 & 0xffffu); u1 += bf2f(w2 >> 16); }
      }
      r0 += (t0 + u0) + v0;
      r1 += (t1 + u1) + v1;
    }
  }
  if (prev >= 0) {
    atomicAdd(&mol_repr[(u64)prev * 128 + c0], r0);
    atomicAdd(&mol_repr[(u64)prev * 128 + c0 + 16], r1);
  }
}

// ---------------- final tiny MLP per molecule ----------------
__global__ void final_mlp(const float* __restrict__ mol_repr,
                          const float* __restrict__ fc1_w, const float* __restrict__ fc1_b,
                          const float* __restrict__ fc2_w, const float* __restrict__ fc2_b,
                          const float* __restrict__ out_w, const float* __restrict__ out_b,
                          float* __restrict__ out) {
  int m = blockIdx.x, j = threadIdx.x;
  __shared__ float h1sh[64], h2sh[64];
  const float* mr = mol_repr + (u64)m * DF;
  float acc = fc1_b[j];
  for (int d = 0; d < DF; d++) acc = fmaf(mr[d], fc1_w[d * 64 + j], acc);
  h1sh[j] = fmaxf(acc, 0.f);
  __syncthreads();
  acc = fc2_b[j];
  for (int k = 0; k < 64; k++) acc = fmaf(h1sh[k], fc2_w[k * 64 + j], acc);
  h2sh[j] = fmaxf(acc, 0.f);
  __syncthreads();
  if (j < NOUT) {
    acc = out_b[j];
    for (int k = 0; k < 64; k++) acc = fmaf(h2sh[k], out_w[k * NOUT + j], acc);
    out[(u64)m * NOUT + j] = acc;
  }
}

extern "C" void kernel_launch(void* const* d_in, const int* in_sizes, int n_in,
                              void* d_out, int out_size, void* d_ws, size_t ws_size,
                              hipStream_t stream) {
  const float* states = (const float*)d_in[0];
  const float* Win    = (const float*)d_in[1];
  const float* b_in   = (const float*)d_in[2];
  const float* Wh     = (const float*)d_in[3];
  const float* b_h    = (const float*)d_in[4];
  const float* Wout   = (const float*)d_in[5];
  const float* b_out  = (const float*)d_in[6];
  const float* fc1_w  = (const float*)d_in[7];
  const float* fc1_b  = (const float*)d_in[8];
  const float* fc2_w  = (const float*)d_in[9];
  const float* fc2_b  = (const float*)d_in[10];
  const float* out_w  = (const float*)d_in[11];
  const float* out_b  = (const float*)d_in[12];
  const int* src      = (const int*)d_in[13];
  const int* dst      = (const int*)d_in[14];
  const int* mol_ids  = (const int*)d_in[15];

  char* ws = (char*)d_ws;
  u64 o = 0;
  auto alloc = [&](u64 bytes) {
    void* p = ws + o;
    o += (bytes + 255) & ~255ull;
    return p;
  };
  unsigned* m_buf = (unsigned*)alloc((u64)NE * 64 * 4);   // worst-case R = NE
  ushort_t* PQb  = (ushort_t*)alloc((u64)NA * DF * 2);
  ushort_t* WpB  = (ushort_t*)alloc(3 * 16384 * 2);
  ushort_t* WhB  = (ushort_t*)alloc(3 * 4096 * 2);
  ushort_t* WoB  = (ushort_t*)alloc(3 * 8192 * 2);
  // zero-init block (single memset)
  char* zbase    = ws + o;
  float* molr    = (float*)alloc((u64)NMOL * DF * 4);
  int* counts    = (int*)alloc((u64)NA * 4);
  int* cursor    = (int*)alloc((u64)NA * 4);
  int* mcnt      = (int*)alloc(NMOL * 4);
  int* mcur      = (int*)alloc(NMOL * 4);
  u64 zbytes     = (u64)((ws + o) - zbase);
  int* row_ptr   = (int*)alloc((u64)(NA + 1) * 4);
  int* mrow      = (int*)alloc((NMOL + 1) * 4);
  unsigned* ds_pack = (unsigned*)alloc((u64)NE * 4);
  int* mol_sorted = (int*)alloc((u64)NA * 4);
  int* scan_tmp  = (int*)alloc((u64)NA * 4);
  int* blk_sums  = (int*)alloc(64 * 4);
  int* opos      = (int*)alloc((u64)(NE + 1) * 4);
  int* etmp      = (int*)alloc((u64)NE * 4);
  int* eblk      = (int*)alloc(512 * 4);
  int* orow      = (int*)alloc((u64)(NA + 1) * 4);
  (void)ws_size; (void)in_sizes; (void)n_in; (void)out_size;

  const int NSCAN = (NA + 1023) / 1024;   // 49
  const int NESCAN = (NE + 1023) / 1024;  // 391

  hipMemsetAsync(zbase, 0, zbytes, stream);

  setup_a<<<(NE + 255) / 256, 256, 0, stream>>>(Win, Wh, Wout, WpB, WhB, WoB,
                                                dst, mol_ids, counts, mcnt);
  scan_phase1<<<NSCAN, 1024, 0, stream>>>(counts, scan_tmp, blk_sums, mcnt, mrow);
  scan_phase3<<<NSCAN, 1024, 0, stream>>>(scan_tmp, blk_sums, row_ptr);
  fill_ab<<<(NE + 255) / 256, 256, 0, stream>>>(src, dst, row_ptr, cursor, ds_pack,
                                                mol_ids, mrow, mcur, mol_sorted);
  escan_p1<<<NESCAN, 1024, 0, stream>>>(ds_pack, etmp, eblk);
  escan_p3<<<NESCAN, 1024, 0, stream>>>(etmp, eblk, opos);
  make_orow<<<(NA + 256) / 256, 256, 0, stream>>>(row_ptr, opos, orow);

  node_proj<<<(NA + 63) / 64, 256, 0, stream>>>(states, WpB, b_in, PQb);
  for (int t = 0; t < NSTEP; t++) {
    edge_msg<<<(NE + 127) / 128, 256, 0, stream>>>(
        PQb, WhB + t * 4096, WoB + t * 8192,
        b_h + t * 64, b_out + t * 128, ds_pack, opos, m_buf);
    if (t < NSTEP - 1) {
      agg_proj<<<(NA + 63) / 64, 256, 0, stream>>>(m_buf, orow,
                                                   WpB + (t + 1) * 16384,
                                                   b_in + (t + 1) * 64, PQb);
    } else {
      agg_mol2<<<(NA + 63) / 64, 256, 0, stream>>>(m_buf, orow, mol_sorted,
                                                   mol_ids, molr);
    }
  }
  final_mlp<<<NMOL, 64, 0, stream>>>(molr, fc1_w, fc1_b, fc2_w, fc2_b, out_w, out_b,
                                     (float*)d_out);
}

// Round 12
// 377.920 us; speedup vs baseline: 1.7463x; 1.0301x over previous
//
#include <hip/hip_runtime.h>

typedef unsigned long long u64;
typedef unsigned short ushort_t;

#define NA 50000
#define NE 400000
#define DF 128
#define HID 64
#define NMOL 256
#define NOUT 32
#define NSTEP 3
#define NPB 782  // node_proj blocks: ceil(NA/64)

typedef __attribute__((ext_vector_type(8))) short short8;
typedef __attribute__((ext_vector_type(8))) unsigned short ushort8;
typedef __attribute__((ext_vector_type(4))) float f32x4;

static __device__ __forceinline__ ushort_t f2bf(float f) {
  union { float f; unsigned u; } v; v.f = f;
  unsigned r = v.u + 0x7fffu + ((v.u >> 16) & 1u);
  return (ushort_t)(r >> 16);
}
static __device__ __forceinline__ float bf2f(unsigned b) {
  union { unsigned u; float f; } v; v.u = b << 16;
  return v.f;
}

// -------- fused setup: pack weights (B-frag order) + degree histograms -----
__global__ void setup_a(const float* __restrict__ Win, const float* __restrict__ Wh,
                        const float* __restrict__ Wout,
                        ushort_t* __restrict__ WpB, ushort_t* __restrict__ WhB,
                        ushort_t* __restrict__ WoB,
                        const int* __restrict__ dst, const int* __restrict__ mol_ids,
                        int* __restrict__ counts, int* __restrict__ mcnt) {
  int g = blockIdx.x * 256 + threadIdx.x;
  if (g < 3 * 16384) {
    int tt = g / 16384, r = g % 16384;
    int j = r & 7, lane = (r >> 3) & 63, f = r >> 9;
    int kc = f & 3, nt = f >> 2;
    int k = kc * 32 + (lane >> 4) * 8 + j;
    int n = nt * 16 + (lane & 15);
    float v = (n < 64) ? Win[tt * 16384 + k * 64 + n]
                       : Win[tt * 16384 + (128 + k) * 64 + (n - 64)];
    WpB[g] = f2bf(v);
  }
  int g2 = g - 3 * 16384;
  if (g2 >= 0 && g2 < 3 * 4096) {
    int tt = g2 / 4096, r = g2 % 4096;
    int j = r & 7, lane = (r >> 3) & 63, f = r >> 9;
    int kc = f & 1, nt = f >> 1;
    int k = kc * 32 + (lane >> 4) * 8 + j;
    int n = nt * 16 + (lane & 15);
    WhB[g2] = f2bf(Wh[tt * 4096 + k * 64 + n]);
  }
  int g3 = g2 - 3 * 4096;
  if (g3 >= 0 && g3 < 3 * 8192) {
    int tt = g3 / 8192, r = g3 % 8192;
    int j = r & 7, lane = (r >> 3) & 63, f = r >> 9;
    int kc = f & 1, nt = f >> 1;
    int k = kc * 32 + (lane >> 4) * 8 + j;
    int n = nt * 16 + (lane & 15);
    WoB[g3] = f2bf(Wout[tt * 8192 + k * 128 + n]);
  }
  if (g < NE) atomicAdd(&counts[dst[g]], 1);
  if (g < NA) atomicAdd(&mcnt[mol_ids[g]], 1);
}

// per-1024-block inclusive scan of counts; last block also scans mol histogram
__global__ void scan_phase1(const int* __restrict__ counts, int* __restrict__ tmp,
                            int* __restrict__ blk,
                            const int* __restrict__ mcnt, int* __restrict__ mrow) {
  __shared__ int sh[1024];
  int t = threadIdx.x;
  int i = blockIdx.x * 1024 + t;
  sh[t] = (i < NA) ? counts[i] : 0;
  __syncthreads();
  for (int off = 1; off < 1024; off <<= 1) {
    int x = (t >= off) ? sh[t - off] : 0;
    __syncthreads();
    sh[t] += x;
    __syncthreads();
  }
  if (i < NA) tmp[i] = sh[t];
  if (t == 1023) blk[blockIdx.x] = sh[1023];
  if (blockIdx.x == gridDim.x - 1) {  // fold in the molecule scan
    __syncthreads();
    sh[t] = (t < NMOL) ? mcnt[t] : 0;
    __syncthreads();
    for (int off = 1; off < NMOL; off <<= 1) {
      int x = (t >= off && t < NMOL) ? sh[t - off] : 0;
      __syncthreads();
      if (t < NMOL) sh[t] += x;
      __syncthreads();
    }
    if (t < NMOL) mrow[t + 1] = sh[t];
    if (t == 0) mrow[0] = 0;
  }
}

// row_ptr[i+1] = tmp[i] + prefix(blk, bid); prefix computed by wave-reduce
__global__ void scan_phase3(const int* __restrict__ tmp, const int* __restrict__ blk,
                            int* __restrict__ row_ptr) {
  __shared__ int spre_sh;
  int t = threadIdx.x;
  int bid = blockIdx.x;
  if (t < 64) {
    int v = (t < bid) ? blk[t] : 0;  // bid <= 48 < 64
    for (int off = 32; off; off >>= 1) v += __shfl_down(v, off);
    if (t == 0) spre_sh = v;
  }
  __syncthreads();
  int spre = spre_sh;
  int i = bid * 1024 + t;
  if (i < NA) row_ptr[i + 1] = tmp[i] + spre;
  if (i == 0) row_ptr[0] = 0;
}

// scatter edges sorted by dst, packed (dst<<16)|src; + mol_sorted scatter
__global__ void fill_ab(const int* __restrict__ src, const int* __restrict__ dst,
                        const int* __restrict__ row_ptr, int* __restrict__ cursor,
                        unsigned* __restrict__ ds_pack,
                        const int* __restrict__ mol_ids, const int* __restrict__ mrow,
                        int* __restrict__ mcur, int* __restrict__ mol_sorted) {
  int e = blockIdx.x * 256 + threadIdx.x;
  if (e < NE) {
    int d = dst[e];
    int pos = row_ptr[d] + atomicAdd(&cursor[d], 1);
    ds_pack[pos] = ((unsigned)d << 16) | (unsigned)src[e];
  }
  if (e < NA) {
    int m = mol_ids[e];
    int pos = mrow[m] + atomicAdd(&mcur[m], 1);
    mol_sorted[pos] = e;
  }
}

// ---- sub-run scan: opos[e] = index of e's sub-run (4-edge-window x dst) ----
__global__ void escan_p1(const unsigned* __restrict__ ds_pack, int* __restrict__ etmp,
                         int* __restrict__ eblk) {
  __shared__ int sh[1024];
  int t = threadIdx.x;
  int i = blockIdx.x * 1024 + t;
  int f = 0;
  if (i < NE)
    f = ((i & 3) == 0 || (ds_pack[i] >> 16) != (ds_pack[i - 1] >> 16)) ? 1 : 0;
  sh[t] = f;
  __syncthreads();
  for (int off = 1; off < 1024; off <<= 1) {
    int x = (t >= off) ? sh[t - off] : 0;
    __syncthreads();
    sh[t] += x;
    __syncthreads();
  }
  if (i < NE) etmp[i] = sh[t];
  if (t == 1023) eblk[blockIdx.x] = sh[1023];
}

// opos[i] = etmp[i] + prefix(eblk, bid) - 1; prefix via block tree-reduce
__global__ void escan_p3(const int* __restrict__ etmp, const int* __restrict__ eblk,
                         int* __restrict__ opos) {
  __shared__ int red[1024];
  int t = threadIdx.x;
  int bid = blockIdx.x;
  red[t] = (t < bid) ? eblk[t] : 0;  // bid <= 390 < 1024
  __syncthreads();
  for (int off = 512; off; off >>= 1) {
    if (t < off) red[t] += red[t + off];
    __syncthreads();
  }
  int spre = red[0];
  int i = bid * 1024 + t;
  if (i < NE) {
    int v = etmp[i] + spre - 1;
    opos[i] = v;
    if (i == NE - 1) opos[NE] = v + 1;
  }
}

// -------- node projection (blocks < NPB) + orow build (blocks >= NPB) ------
// PQb = bf16(s @ W' [+ b_in on P-cols]);  orow[d] = opos[row_ptr[d]]
__global__ __launch_bounds__(256) void proj_orow(
    const float* __restrict__ s_in, const ushort_t* __restrict__ WpB,
    const float* __restrict__ b_in, ushort_t* __restrict__ PQb,
    const int* __restrict__ row_ptr, const int* __restrict__ opos,
    int* __restrict__ orow) {
  if (blockIdx.x >= NPB) {
    int i = (blockIdx.x - NPB) * 256 + threadIdx.x;
    if (i <= NA) orow[i] = opos[row_ptr[i]];
    return;
  }
  const int t = threadIdx.x;
  const int lane = t & 63, wv = t >> 6, quad = lane >> 4, l15 = lane & 15;
  const int n0 = blockIdx.x * 64 + wv * 16;
  int n = n0 + l15; if (n >= NA) n = NA - 1;
  union { short8 v; ushort_t u[8]; } a[4];
#pragma unroll
  for (int c = 0; c < 4; c++) {
    const float* p = s_in + (u64)n * 128 + c * 32 + quad * 8;
    float4 f0 = *(const float4*)(p);
    float4 f1 = *(const float4*)(p + 4);
    a[c].u[0] = f2bf(f0.x); a[c].u[1] = f2bf(f0.y);
    a[c].u[2] = f2bf(f0.z); a[c].u[3] = f2bf(f0.w);
    a[c].u[4] = f2bf(f1.x); a[c].u[5] = f2bf(f1.y);
    a[c].u[6] = f2bf(f1.z); a[c].u[7] = f2bf(f1.w);
  }
  float binv[4];
#pragma unroll
  for (int nt = 0; nt < 4; nt++) binv[nt] = b_in[nt * 16 + l15];
#pragma unroll
  for (int nt = 0; nt < 8; nt++) {
    f32x4 acc = {0.f, 0.f, 0.f, 0.f};
#pragma unroll
    for (int c = 0; c < 4; c++) {
      short8 b = *(const short8*)&WpB[((nt * 4 + c) * 64 + lane) * 8];
      acc = __builtin_amdgcn_mfma_f32_16x16x32_bf16(a[c].v, b, acc, 0, 0, 0);
    }
    float bias = (nt < 4) ? binv[nt] : 0.f;
#pragma unroll
    for (int r = 0; r < 4; r++) {
      int nn = n0 + quad * 4 + r;
      if (nn < NA) PQb[(u64)nn * 128 + nt * 16 + l15] = f2bf(acc[r] + bias);
    }
  }
}

// ------ fused edge MLP (MFMA) -> packed-bf16 SUB-RUN partial sums ----------
__global__ __launch_bounds__(256) void edge_msg(
    const ushort_t* __restrict__ PQb,
    const ushort_t* __restrict__ WhB, const ushort_t* __restrict__ WoB,
    const float* __restrict__ b_h, const float* __restrict__ b_out,
    const unsigned* __restrict__ ds_pack, const int* __restrict__ opos,
    unsigned* __restrict__ m_buf) {
  __shared__ unsigned eps[128];
  __shared__ int ops[128];
  __shared__ ushort_t h2s[4][16 * 72];  // per-wave 16 x 64 bf16 (reused across i)
  const int t = threadIdx.x;
  const int lane = t & 63, wv = t >> 6, quad = lane >> 4, l15 = lane & 15;
  const long long e0 = (long long)blockIdx.x * 128;  // NE % 128 == 0

  if (t < 128) {
    eps[t] = ds_pack[e0 + t];
    ops[t] = opos[e0 + t];
  }
  float bh[4], bo[8];
#pragma unroll
  for (int nt = 0; nt < 4; nt++) bh[nt] = b_h[nt * 16 + l15];
#pragma unroll
  for (int nt = 0; nt < 8; nt++) bo[nt] = b_out[nt * 16 + l15];
  __syncthreads();

  // prefetch both tiles' gathers (8 outstanding 16B loads)
  union { ushort8 v; ushort_t u[8]; } pv[2][2], qv[2][2];
#pragma unroll
  for (int i = 0; i < 2; i++) {
    unsigned pk = eps[wv * 32 + i * 16 + l15];
    int da = pk >> 16, sa = pk & 0xffffu;
#pragma unroll
    for (int c = 0; c < 2; c++) {
      const int col = c * 32 + quad * 8;
      pv[i][c].v = *(const ushort8*)&PQb[(u64)da * 128 + col];
      qv[i][c].v = *(const ushort8*)&PQb[(u64)sa * 128 + 64 + col];
    }
  }

#pragma unroll
  for (int i = 0; i < 2; i++) {
    const int ebl = wv * 32 + i * 16;  // block-local tile base

    // A-frag of h1 = relu(P'[dst] + Q[src]) from prefetched regs
    union { short8 v; ushort_t u[8]; } a1[2];
#pragma unroll
    for (int c = 0; c < 2; c++) {
#pragma unroll
      for (int k = 0; k < 8; k++)
        a1[c].u[k] = f2bf(fmaxf(bf2f(pv[i][c].u[k]) + bf2f(qv[i][c].u[k]), 0.f));
    }

    // h2 = relu(h1 @ Wh + b_h)
    f32x4 acc1[4];
#pragma unroll
    for (int nt = 0; nt < 4; nt++) {
      f32x4 acc = {0.f, 0.f, 0.f, 0.f};
#pragma unroll
      for (int c = 0; c < 2; c++) {
        short8 b = *(const short8*)&WhB[((nt * 2 + c) * 64 + lane) * 8];
        acc = __builtin_amdgcn_mfma_f32_16x16x32_bf16(a1[c].v, b, acc, 0, 0, 0);
      }
      acc1[nt] = acc;
    }
    // D-layout -> row-major LDS (wave-private; same-wave RAW/WAR via lgkmcnt)
    ushort_t* hb = h2s[wv];
#pragma unroll
    for (int nt = 0; nt < 4; nt++)
#pragma unroll
      for (int r = 0; r < 4; r++)
        hb[(quad * 4 + r) * 72 + nt * 16 + l15] =
            f2bf(fmaxf(acc1[nt][r] + bh[nt], 0.f));

    union { short8 v; ushort_t u[8]; } a2[2];
#pragma unroll
    for (int c = 0; c < 2; c++)
      a2[c].v = *(const short8*)&hb[l15 * 72 + c * 32 + quad * 8];

    // m = relu(h2 @ Wout + b_out)
    f32x4 acc2[8];
#pragma unroll
    for (int nt = 0; nt < 8; nt++) {
      f32x4 acc = {0.f, 0.f, 0.f, 0.f};
#pragma unroll
      for (int c = 0; c < 2; c++) {
        short8 b = *(const short8*)&WoB[((nt * 2 + c) * 64 + lane) * 8];
        acc = __builtin_amdgcn_mfma_f32_16x16x32_bf16(a2[c].v, b, acc, 0, 0, 0);
      }
      acc2[nt] = acc;
    }

    // segmented sub-run flush: fp32 partials over the quad's 4 edges
    {
      const int base = ebl + quad * 4;
      int prev = (int)(eps[base] >> 16);
      int orow_ = ops[base];
      float run[8];
#pragma unroll
      for (int nt = 0; nt < 8; nt++) run[nt] = 0.f;
#pragma unroll
      for (int r = 0; r < 4; r++) {
        int er = base + r;
        int dcur = (int)(eps[er] >> 16);
        if (dcur != prev) {
          unsigned* rowp = m_buf + (u64)orow_ * 64;
#pragma unroll
          for (int k = 0; k < 4; k++)
            rowp[k * 16 + l15] =
                (unsigned)f2bf(run[2 * k]) | ((unsigned)f2bf(run[2 * k + 1]) << 16);
#pragma unroll
          for (int nt = 0; nt < 8; nt++) run[nt] = 0.f;
          prev = dcur; orow_ = ops[er];
        }
#pragma unroll
        for (int nt = 0; nt < 8; nt++)
          run[nt] += fmaxf(acc2[nt][r] + bo[nt], 0.f);
      }
      unsigned* rowp = m_buf + (u64)orow_ * 64;
#pragma unroll
      for (int k = 0; k < 4; k++)
        rowp[k * 16 + l15] =
            (unsigned)f2bf(run[2 * k]) | ((unsigned)f2bf(run[2 * k + 1]) << 16);
    }
  }
}

// ---- fused dst aggregation + projection; bounds staged in LDS -------------
__global__ __launch_bounds__(256) void agg_proj(
    const unsigned* __restrict__ m_buf, const int* __restrict__ orow,
    const ushort_t* __restrict__ WpB, const float* __restrict__ b_in,
    ushort_t* __restrict__ PQb) {
  __shared__ ushort_t a_s[64 * 136];  // 64 rows x 128 bf16, pitch 136
  __shared__ int obs_s[65];
  const int t = threadIdx.x;
  const int lane = t & 63, wv = t >> 6, quad = lane >> 4, l15 = lane & 15;
  const int n0 = blockIdx.x * 64;
  if (t < 65) {
    int idx = n0 + t; if (idx > NA) idx = NA;
    obs_s[t] = orow[idx];
  }
  __syncthreads();

  for (int r = 0; r < 16; r++) {
    const int d = n0 + wv * 16 + r;
    float s0 = 0.f, s1 = 0.f;
    if (d < NA) {
      int ob = obs_s[wv * 16 + r], oe = obs_s[wv * 16 + r + 1];
      int n = oe - ob;
      float t0 = 0.f, t1 = 0.f, u0 = 0.f, u1 = 0.f, v0 = 0.f, v1 = 0.f;
      int full = n & ~3;
      int e = ob;
      for (; e < ob + full; e += 4) {
        unsigned w0 = m_buf[(u64)(e + 0) * 64 + lane];
        unsigned w1 = m_buf[(u64)(e + 1) * 64 + lane];
        unsigned w2 = m_buf[(u64)(e + 2) * 64 + lane];
        unsigned w3 = m_buf[(u64)(e + 3) * 64 + lane];
        s0 += bf2f(w0 & 0xffffu); s1 += bf2f(w0 >> 16);
        t0 += bf2f(w1 & 0xffffu); t1 += bf2f(w1 >> 16);
        u0 += bf2f(w2 & 0xffffu); u1 += bf2f(w2 >> 16);
        v0 += bf2f(w3 & 0xffffu); v1 += bf2f(w3 >> 16);
      }
      int rem = n - full;
      if (rem > 0) {
        int i1 = (rem > 1) ? e + 1 : e;
        int i2 = (rem > 2) ? e + 2 : e;
        unsigned w0 = m_buf[(u64)e * 64 + lane];
        unsigned w1 = m_buf[(u64)i1 * 64 + lane];
        unsigned w2 = m_buf[(u64)i2 * 64 + lane];
        s0 += bf2f(w0 & 0xffffu); s1 += bf2f(w0 >> 16);
        if (rem > 1) { t0 += bf2f(w1 & 0xffffu); t1 += bf2f(w1 >> 16); }
        if (rem > 2) { u0 += bf2f(w2 & 0xffffu); u1 += bf2f(w2 >> 16); }
      }
      s0 = (s0 + t0) + (u0 + v0);
      s1 = (s1 + t1) + (u1 + v1);
    }
    const int row = wv * 16 + r;
    a_s[row * 136 + quad * 32 + l15] = f2bf(s0);
    a_s[row * 136 + quad * 32 + 16 + l15] = f2bf(s1);
  }
  // wave-private tile: same-wave LDS RAW ordered by lgkmcnt, no barrier

  float binv[4];
#pragma unroll
  for (int nt = 0; nt < 4; nt++) binv[nt] = b_in[nt * 16 + l15];
  short8 a[4];
#pragma unroll
  for (int c = 0; c < 4; c++)
    a[c] = *(const short8*)&a_s[(wv * 16 + l15) * 136 + c * 32 + quad * 8];
#pragma unroll
  for (int nt = 0; nt < 8; nt++) {
    f32x4 acc = {0.f, 0.f, 0.f, 0.f};
#pragma unroll
    for (int c = 0; c < 4; c++) {
      short8 b = *(const short8*)&WpB[((nt * 4 + c) * 64 + lane) * 8];
      acc = __builtin_amdgcn_mfma_f32_16x16x32_bf16(a[c], b, acc, 0, 0, 0);
    }
    float bias = (nt < 4) ? binv[nt] : 0.f;
#pragma unroll
    for (int r = 0; r < 4; r++) {
      int nn = n0 + wv * 16 + quad * 4 + r;
      if (nn < NA) PQb[(u64)nn * 128 + nt * 16 + l15] = f2bf(acc[r] + bias);
    }
  }
}

// ---- final aggregation: m_buf sub-runs -> per-mol sums; bounds in LDS -----
__global__ __launch_bounds__(256) void agg_mol2(
    const unsigned* __restrict__ m_buf, const int* __restrict__ orow,
    const int* __restrict__ mol_sorted, const int* __restrict__ mol_ids,
    float* __restrict__ mol_repr) {
  __shared__ int mids[64], obs[64], oes[64];
  const int t = threadIdx.x;
  const int lane = t & 63, wv = t >> 6;
  const int base = blockIdx.x * 64;
  if (t < 64) {
    int idx = base + t;
    int r = (idx < NA) ? mol_sorted[idx] : 0;
    mids[t] = (idx < NA) ? mol_ids[r] : -1;
    obs[t] = orow[r];
    oes[t] = orow[r + 1];
  }
  __syncthreads();
  const int c0 = (lane >> 4) * 32 + (lane & 15);  // unpacked cols c0, c0+16
  float r0 = 0.f, r1 = 0.f;
  int prev = mids[wv * 16];
  for (int i = 0; i < 16; i++) {
    int li = wv * 16 + i;
    int m = mids[li];
    if (m != prev) {
      if (prev >= 0) {
        atomicAdd(&mol_repr[(u64)prev * 128 + c0], r0);
        atomicAdd(&mol_repr[(u64)prev * 128 + c0 + 16], r1);
      }
      r0 = 0.f; r1 = 0.f; prev = m;
    }
    if (m >= 0) {
      int ob = obs[li], oe = oes[li];
      int n = oe - ob;
      float t0 = 0.f, t1 = 0.f, u0 = 0.f, u1 = 0.f, v0 = 0.f, v1 = 0.f;
      int full = n & ~3;
      int e = ob;
      for (; e < ob + full; e += 4) {
        unsigned w0 = m_buf[(u64)(e + 0) * 64 + lane];
        unsigned w1 = m_buf[(u64)(e + 1) * 64 + lane];
        unsigned w2 = m_buf[(u64)(e + 2) * 64 + lane];
        unsigned w3 = m_buf[(u64)(e + 3) * 64 + lane];
        r0 += bf2f(w0 & 0xffffu); r1 += bf2f(w0 >> 16);
        t0 += bf2f(w1 & 0xffffu); t1 += bf2f(w1 >> 16);
        u0 += bf2f(w2 & 0xffffu); u1 += bf2f(w2 >> 16);
        v0 += bf2f(w3 & 0xffffu); v1 += bf2f(w3 >> 16);
      }
      int rem = n - full;
      if (rem > 0) {
        int i1 = (rem > 1) ? e + 1 : e;
        int i2 = (rem > 2) ? e + 2 : e;
        unsigned w0 = m_buf[(u64)e * 64 + lane];
        unsigned w1 = m_buf[(u64)i1 * 64 + lane];
        unsigned w2 = m_buf[(u64)i2 * 64 + lane];
        r0 += bf2f(w0 & 0xffffu); r1 += bf2f(w0 >> 16);
        if (rem > 1) { t0 += bf2f(w1 & 0xffffu); t1 += bf2f(w1 >> 16); }
        if (rem > 2) { u0 += bf2f(w2 & 0xffffu); u1 += bf2f(w2 >> 16); }
      }
      r0 += (t0 + u0) + v0;
      r1 += (t1 + u1) + v1;
    }
  }
  if (prev >= 0) {
    atomicAdd(&mol_repr[(u64)prev * 128 + c0], r0);
    atomicAdd(&mol_repr[(u64)prev * 128 + c0 + 16], r1);
  }
}

// ---------------- final tiny MLP per molecule ----------------
__global__ void final_mlp(const float* __restrict__ mol_repr,
                          const float* __restrict__ fc1_w, const float* __restrict__ fc1_b,
                          const float* __restrict__ fc2_w, const float* __restrict__ fc2_b,
                          const float* __restrict__ out_w, const float* __restrict__ out_b,
                          float* __restrict__ out) {
  int m = blockIdx.x, j = threadIdx.x;
  __shared__ float h1sh[64], h2sh[64];
  const float* mr = mol_repr + (u64)m * DF;
  float acc = fc1_b[j];
  for (int d = 0; d < DF; d++) acc = fmaf(mr[d], fc1_w[d * 64 + j], acc);
  h1sh[j] = fmaxf(acc, 0.f);
  __syncthreads();
  acc = fc2_b[j];
  for (int k = 0; k < 64; k++) acc = fmaf(h1sh[k], fc2_w[k * 64 + j], acc);
  h2sh[j] = fmaxf(acc, 0.f);
  __syncthreads();
  if (j < NOUT) {
    acc = out_b[j];
    for (int k = 0; k < 64; k++) acc = fmaf(h2sh[k], out_w[k * NOUT + j], acc);
    out[(u64)m * NOUT + j] = acc;
  }
}

extern "C" void kernel_launch(void* const* d_in, const int* in_sizes, int n_in,
                              void* d_out, int out_size, void* d_ws, size_t ws_size,
                              hipStream_t stream) {
  const float* states = (const float*)d_in[0];
  const float* Win    = (const float*)d_in[1];
  const float* b_in   = (const float*)d_in[2];
  const float* Wh     = (const float*)d_in[3];
  const float* b_h    = (const float*)d_in[4];
  const float* Wout   = (const float*)d_in[5];
  const float* b_out  = (const float*)d_in[6];
  const float* fc1_w  = (const float*)d_in[7];
  const float* fc1_b  = (const float*)d_in[8];
  const float* fc2_w  = (const float*)d_in[9];
  const float* fc2_b  = (const float*)d_in[10];
  const float* out_w  = (const float*)d_in[11];
  const float* out_b  = (const float*)d_in[12];
  const int* src      = (const int*)d_in[13];
  const int* dst      = (const int*)d_in[14];
  const int* mol_ids  = (const int*)d_in[15];

  char* ws = (char*)d_ws;
  u64 o = 0;
  auto alloc = [&](u64 bytes) {
    void* p = ws + o;
    o += (bytes + 255) & ~255ull;
    return p;
  };
  unsigned* m_buf = (unsigned*)alloc((u64)NE * 64 * 4);   // worst-case R = NE
  ushort_t* PQb  = (ushort_t*)alloc((u64)NA * DF * 2);
  ushort_t* WpB  = (ushort_t*)alloc(3 * 16384 * 2);
  ushort_t* WhB  = (ushort_t*)alloc(3 * 4096 * 2);
  ushort_t* WoB  = (ushort_t*)alloc(3 * 8192 * 2);
  // zero-init block (single memset)
  char* zbase    = ws + o;
  float* molr    = (float*)alloc((u64)NMOL * DF * 4);
  int* counts    = (int*)alloc((u64)NA * 4);
  int* cursor    = (int*)alloc((u64)NA * 4);
  int* mcnt      = (int*)alloc(NMOL * 4);
  int* mcur      = (int*)alloc(NMOL * 4);
  u64 zbytes     = (u64)((ws + o) - zbase);
  int* row_ptr   = (int*)alloc((u64)(NA + 1) * 4);
  int* mrow      = (int*)alloc((NMOL + 1) * 4);
  unsigned* ds_pack = (unsigned*)alloc((u64)NE * 4);
  int* mol_sorted = (int*)alloc((u64)NA * 4);
  int* scan_tmp  = (int*)alloc((u64)NA * 4);
  int* blk_sums  = (int*)alloc(64 * 4);
  int* opos      = (int*)alloc((u64)(NE + 1) * 4);
  int* etmp      = (int*)alloc((u64)NE * 4);
  int* eblk      = (int*)alloc(512 * 4);
  int* orow      = (int*)alloc((u64)(NA + 1) * 4);
  (void)ws_size; (void)in_sizes; (void)n_in; (void)out_size;

  const int NSCAN = (NA + 1023) / 1024;   // 49
  const int NESCAN = (NE + 1023) / 1024;  // 391
  const int OROWB = (NA + 1 + 255) / 256; // 196

  hipMemsetAsync(zbase, 0, zbytes, stream);

  setup_a<<<(NE + 255) / 256, 256, 0, stream>>>(Win, Wh, Wout, WpB, WhB, WoB,
                                                dst, mol_ids, counts, mcnt);
  scan_phase1<<<NSCAN, 1024, 0, stream>>>(counts, scan_tmp, blk_sums, mcnt, mrow);
  scan_phase3<<<NSCAN, 1024, 0, stream>>>(scan_tmp, blk_sums, row_ptr);
  fill_ab<<<(NE + 255) / 256, 256, 0, stream>>>(src, dst, row_ptr, cursor, ds_pack,
                                                mol_ids, mrow, mcur, mol_sorted);
  escan_p1<<<NESCAN, 1024, 0, stream>>>(ds_pack, etmp, eblk);
  escan_p3<<<NESCAN, 1024, 0, stream>>>(etmp, eblk, opos);

  proj_orow<<<NPB + OROWB, 256, 0, stream>>>(states, WpB, b_in, PQb,
                                             row_ptr, opos, orow);
  for (int t = 0; t < NSTEP; t++) {
    edge_msg<<<(NE + 127) / 128, 256, 0, stream>>>(
        PQb, WhB + t * 4096, WoB + t * 8192,
        b_h + t * 64, b_out + t * 128, ds_pack, opos, m_buf);
    if (t < NSTEP - 1) {
      agg_proj<<<(NA + 63) / 64, 256, 0, stream>>>(m_buf, orow,
                                                   WpB + (t + 1) * 16384,
                                                   b_in + (t + 1) * 64, PQb);
    } else {
      agg_mol2<<<(NA + 63) / 64, 256, 0, stream>>>(m_buf, orow, mol_sorted,
                                                   mol_ids, molr);
    }
  }
  final_mlp<<<NMOL, 64, 0, stream>>>(molr, fc1_w, fc1_b, fc2_w, fc2_b, out_w, out_b,
                                     (float*)d_out);
}